// Round 4
// baseline (767.845 us; speedup 1.0000x reference)
//
#include <hip/hip_runtime.h>
#include <math.h>

#define NS 10000
#define LSEQ 32
#define DDIM 300
#define HDIM 300
#define BB 256
#define NMAX 128
#define MMAX 128
#define EPSR 0.1f
#define SITERS 50

// ------- K1: embedding + masked mean pool -> enc [NS, D], float4 ----------
__global__ __launch_bounds__(256) void k_embed(const int* __restrict__ data,
                                               const float* __restrict__ emb,
                                               float* __restrict__ enc) {
  __shared__ int ids[LSEQ];
  __shared__ __align__(16) float4 part[3][76];
  int s = blockIdx.x;
  int tid = threadIdx.x;
  if (tid < LSEQ) ids[tid] = data[s * LSEQ + tid];
  __syncthreads();
  int cnt = 0;
#pragma unroll
  for (int t = 0; t < LSEQ; ++t) cnt += (ids[t] != 0) ? 1 : 0;
  int g = tid / 75, d = tid - g * 75;
  const float4* emb4 = (const float4*)emb;
  if (g < 3) {
    float4 acc = make_float4(0.f, 0.f, 0.f, 0.f);
    for (int t = g; t < LSEQ; t += 3) {
      int id = ids[t];
      if (id != 0) {
        float4 e = emb4[(size_t)id * 75 + d];
        acc.x += e.x; acc.y += e.y; acc.z += e.z; acc.w += e.w;
      }
    }
    part[g][d] = acc;
  }
  __syncthreads();
  if (g == 0) {
    float4 a = part[0][d], b = part[1][d], c = part[2][d];
    float inv = 1.f / (float)(cnt > 0 ? cnt : 1);
    float4 r = make_float4((a.x + b.x + c.x) * inv, (a.y + b.y + c.y) * inv,
                           (a.z + b.z + c.z) * inv, (a.w + b.w + c.w) * inv);
    ((float4*)enc)[(size_t)s * 75 + d] = r;
  }
}

// ------- K2: tiled f32 GEMM 128x64 tile, 8x4 micro, bias+relu opts ---------
__global__ __launch_bounds__(256) void k_gemm(
    const float* __restrict__ A, const float* __restrict__ W,
    const float* __restrict__ bias, float* __restrict__ C,
    int M, int N, int K, int relu) {
  __shared__ __align__(16) float As[16][132];
  __shared__ __align__(16) float Ws[16][68];
  int tid = threadIdx.x, tx = tid & 15, ty = tid >> 4;
  int m0 = blockIdx.x * 128, n0 = blockIdx.y * 64;
  float acc[8][4] = {};
  for (int k0 = 0; k0 < K; k0 += 16) {
    for (int l = tid; l < 2048; l += 256) {
      int kk = l & 15, mm = l >> 4;
      int m = m0 + mm, k = k0 + kk;
      As[kk][mm] = (m < M && k < K) ? A[(size_t)m * K + k] : 0.f;
    }
    for (int l = tid; l < 1024; l += 256) {
      int nn = l & 63, kk = l >> 6;
      int n = n0 + nn, k = k0 + kk;
      Ws[kk][nn] = (n < N && k < K) ? W[(size_t)k * N + n] : 0.f;
    }
    __syncthreads();
#pragma unroll
    for (int kk = 0; kk < 16; ++kk) {
      float4 a0 = *(const float4*)&As[kk][ty * 8];
      float4 a1 = *(const float4*)&As[kk][ty * 8 + 4];
      float4 wv = *(const float4*)&Ws[kk][tx * 4];
      float a[8] = {a0.x, a0.y, a0.z, a0.w, a1.x, a1.y, a1.z, a1.w};
      float w[4] = {wv.x, wv.y, wv.z, wv.w};
#pragma unroll
      for (int i = 0; i < 8; ++i)
#pragma unroll
        for (int j = 0; j < 4; ++j) acc[i][j] += a[i] * w[j];
    }
    __syncthreads();
  }
#pragma unroll
  for (int i = 0; i < 8; ++i) {
    int m = m0 + ty * 8 + i;
    if (m >= M) continue;
    int nb = n0 + tx * 4;
    if (nb + 3 < N) {
      float4 v;
      v.x = acc[i][0] + (bias ? bias[nb + 0] : 0.f);
      v.y = acc[i][1] + (bias ? bias[nb + 1] : 0.f);
      v.z = acc[i][2] + (bias ? bias[nb + 2] : 0.f);
      v.w = acc[i][3] + (bias ? bias[nb + 3] : 0.f);
      if (relu) {
        v.x = v.x > 0.f ? v.x : 0.f; v.y = v.y > 0.f ? v.y : 0.f;
        v.z = v.z > 0.f ? v.z : 0.f; v.w = v.w > 0.f ? v.w : 0.f;
      }
      *(float4*)&C[(size_t)m * N + nb] = v;
    } else {
#pragma unroll
      for (int j = 0; j < 4; ++j) {
        int n = nb + j;
        if (n >= N) continue;
        float v = acc[i][j] + (bias ? bias[n] : 0.f);
        if (relu) v = v > 0.f ? v : 0.f;
        C[(size_t)m * N + n] = v;
      }
    }
  }
}

// ---------------- K3: row-normalize henc -> hn [NS, H] ---------------------
__global__ __launch_bounds__(256) void k_norm(const float* __restrict__ henc,
                                              float* __restrict__ hn) {
  int s = blockIdx.x * 4 + (threadIdx.x >> 6);
  int lane = threadIdx.x & 63;
  if (s >= NS) return;
  const float* src = henc + (size_t)s * HDIM;
  float v[5];
  float ss = 0.f;
#pragma unroll
  for (int q = 0; q < 5; ++q) {
    int d = lane + q * 64;
    v[q] = (d < HDIM) ? src[d] : 0.f;
    ss += v[q] * v[q];
  }
#pragma unroll
  for (int off = 32; off > 0; off >>= 1) ss += __shfl_down(ss, off, 64);
  ss = __shfl(ss, 0, 64);
  float inv = 1.f / (sqrtf(ss) + 1e-8f);
  float* dst = hn + (size_t)s * HDIM;
#pragma unroll
  for (int q = 0; q < 5; ++q) {
    int d = lane + q * 64;
    if (d < HDIM) dst[d] = v[q] * inv;
  }
}

// --- K4: cost as 64x64-tiled GEMM (K=300) w/ gather + fused exp epilogue ---
__global__ __launch_bounds__(256) void k_cost(
    const float* __restrict__ hn, const int* __restrict__ ridx,
    const int* __restrict__ cidx, const int* __restrict__ rlen,
    const int* __restrict__ clen, float* __restrict__ Kmat) {
  int b = blockIdx.z;
  int r0 = blockIdx.x * 64, c0 = blockIdx.y * 64;
  int rl = rlen[b], cl = clen[b];
  float* Kg = Kmat + (size_t)b * NMAX * MMAX;
  int tid = threadIdx.x, tx = tid & 15, ty = tid >> 4;
  if (r0 >= rl || c0 >= cl) {
    for (int l = tid; l < 64 * 16; l += 256) {
      int i = l >> 4, j = (l & 15) << 2;
      *(float4*)&Kg[(size_t)(r0 + i) * MMAX + c0 + j] =
          make_float4(0.f, 0.f, 0.f, 0.f);
    }
    return;
  }
  __shared__ int rix[64], cix[64];
  __shared__ __align__(16) float As[16][68];
  __shared__ __align__(16) float Bs[16][68];
  if (tid < 64) rix[tid] = ridx[b * NMAX + r0 + tid];
  else if (tid < 128) cix[tid - 64] = cidx[b * MMAX + c0 + tid - 64];
  __syncthreads();
  float acc[4][4] = {};
  for (int k0 = 0; k0 < HDIM; k0 += 16) {
    for (int l = tid; l < 1024; l += 256) {
      int kk = l & 15, mm = l >> 4;
      int k = k0 + kk;
      As[kk][mm] = (k < HDIM) ? hn[(size_t)rix[mm] * HDIM + k] : 0.f;
    }
    for (int l = tid; l < 1024; l += 256) {
      int kk = l & 15, mm = l >> 4;
      int k = k0 + kk;
      Bs[kk][mm] = (k < HDIM) ? hn[(size_t)cix[mm] * HDIM + k] : 0.f;
    }
    __syncthreads();
#pragma unroll
    for (int kk = 0; kk < 16; ++kk) {
      float4 av = *(const float4*)&As[kk][ty * 4];
      float4 bv = *(const float4*)&Bs[kk][tx * 4];
      float a[4] = {av.x, av.y, av.z, av.w};
      float w[4] = {bv.x, bv.y, bv.z, bv.w};
#pragma unroll
      for (int i = 0; i < 4; ++i)
#pragma unroll
        for (int j = 0; j < 4; ++j) acc[i][j] += a[i] * w[j];
    }
    __syncthreads();
  }
#pragma unroll
  for (int i = 0; i < 4; ++i) {
    int n = r0 + ty * 4 + i;
    float4 kv;
    float* kvp = &kv.x;
#pragma unroll
    for (int j = 0; j < 4; ++j) {
      int m = c0 + tx * 4 + j;
      kvp[j] = (n < rl && m < cl) ? expf((acc[i][j] - 1.f) / EPSR) : 0.f;
    }
    *(float4*)&Kg[(size_t)n * MMAX + c0 + tx * 4] = kv;
  }
}

// --------- K5: Sinkhorn, K held in VGPRs (kr row / kt col slices) ----------
__global__ __launch_bounds__(512) void k_sinkhorn(
    float* __restrict__ Kmat, const int* __restrict__ rlen,
    const int* __restrict__ clen) {
  __shared__ __align__(16) float vq[4][36];
  __shared__ __align__(16) float uq[4][36];
  int b = blockIdx.x;
  int tid = threadIdx.x;
  int n = tid >> 2, q = tid & 3;
  int rl = rlen[b], cl = clen[b];
  float* Kg = Kmat + (size_t)b * NMAX * MMAX;
  float kr[32], kt[32];
  const float4* Kg4 = (const float4*)(Kg + (size_t)n * MMAX + 32 * q);
#pragma unroll
  for (int t = 0; t < 8; ++t) *(float4*)&kr[4 * t] = Kg4[t];
#pragma unroll
  for (int j = 0; j < 32; ++j) kt[j] = Kg[(size_t)(32 * q + j) * MMAX + n];
  if (tid < 128) vq[tid >> 5][tid & 31] = (tid < cl) ? 1.f : 0.f;
  float av = (n < rl) ? 1.f / (float)rl : 0.f;
  float bv = (n < cl) ? 1.f / (float)cl : 0.f;
  float un = 0.f;
  __syncthreads();
  for (int it = 0; it < SITERS; ++it) {
    float s = 0.f;
#pragma unroll
    for (int t = 0; t < 8; ++t) {
      float4 vv = *(const float4*)&vq[q][4 * t];
      s += kr[4 * t + 0] * vv.x + kr[4 * t + 1] * vv.y +
           kr[4 * t + 2] * vv.z + kr[4 * t + 3] * vv.w;
    }
    s += __shfl_xor(s, 1, 64);
    s += __shfl_xor(s, 2, 64);
    un = (n < rl) ? av / s : 0.f;
    if (q == 0) uq[n >> 5][n & 31] = un;
    __syncthreads();
    float s2 = 0.f;
#pragma unroll
    for (int t = 0; t < 8; ++t) {
      float4 uu = *(const float4*)&uq[q][4 * t];
      s2 += kt[4 * t + 0] * uu.x + kt[4 * t + 1] * uu.y +
            kt[4 * t + 2] * uu.z + kt[4 * t + 3] * uu.w;
    }
    s2 += __shfl_xor(s2, 1, 64);
    s2 += __shfl_xor(s2, 2, 64);
    float vm = (n < cl) ? bv / s2 : 0.f;
    if (q == 0) vq[n >> 5][n & 31] = vm;
    __syncthreads();
  }
  float4* Pg4 = (float4*)(Kg + (size_t)n * MMAX + 32 * q);
#pragma unroll
  for (int t = 0; t < 8; ++t) {
    float4 vv = *(const float4*)&vq[q][4 * t];
    float4 p;
    p.x = un * kr[4 * t + 0] * vv.x;
    p.y = un * kr[4 * t + 1] * vv.y;
    p.z = un * kr[4 * t + 2] * vv.z;
    p.w = un * kr[4 * t + 3] * vv.w;
    Pg4[t] = p;
  }
}

// ---- K6: attend + compare + masked sum; one block per (col-tile, batch) ---
// SIDE 0: main=rows (P[i][k]); SIDE 1: main=cols (P[k][j]). No atomics:
// block owns cols [c0,c0+64) of batch b, loops m-tiles, writes result once.
template <int SIDE>
__global__ __launch_bounds__(256) void k_att_cmp(
    const float* __restrict__ P, const float* __restrict__ Hc,
    const float* __restrict__ Hcb, const int* __restrict__ idx_main,
    const int* __restrict__ idx_other, const int* __restrict__ len_main,
    const int* __restrict__ len_other, const float* __restrict__ bc,
    float* __restrict__ outacc) {
  int b = blockIdx.y;
  int c0 = blockIdx.x * 64;
  int lm = len_main[b], lo = len_other[b];
  __shared__ __align__(16) float Ps[16][68];
  __shared__ __align__(16) float Gs[16][68];
  __shared__ int iox[NMAX];
  __shared__ int imx[NMAX];
  int tid = threadIdx.x, tx = tid & 15, ty = tid >> 4;
  if (tid < 128) iox[tid] = idx_other[b * NMAX + tid];
  else imx[tid - 128] = idx_main[b * NMAX + tid - 128];
  __syncthreads();
  const float* Pb = P + (size_t)b * NMAX * MMAX;
  float colsum[4] = {0.f, 0.f, 0.f, 0.f};
  int nkc = (lo + 15) >> 4;  // P is zero beyond lo -> no k-tail masking needed
  for (int m0 = 0; m0 < lm; m0 += 64) {
    float acc[4][4] = {};
    for (int kc = 0; kc < nkc; ++kc) {
      int k0 = kc << 4;
      if (SIDE == 0) {
        for (int l = tid; l < 1024; l += 256) {
          int kk = l & 15, mm = l >> 4;
          Ps[kk][mm] = Pb[(size_t)(m0 + mm) * MMAX + k0 + kk];
        }
      } else {
        for (int l = tid; l < 1024; l += 256) {
          int mm = l & 63, kk = l >> 6;
          Ps[kk][mm] = Pb[(size_t)(k0 + kk) * MMAX + m0 + mm];
        }
      }
      for (int l = tid; l < 1024; l += 256) {
        int jj = l & 63, kk = l >> 6;
        int col = c0 + jj;
        Gs[kk][jj] = (col < HDIM) ? Hcb[(size_t)iox[k0 + kk] * HDIM + col] : 0.f;
      }
      __syncthreads();
#pragma unroll
      for (int kk = 0; kk < 16; ++kk) {
        float4 av = *(const float4*)&Ps[kk][ty * 4];
        float4 gv = *(const float4*)&Gs[kk][tx * 4];
        float a[4] = {av.x, av.y, av.z, av.w};
        float g[4] = {gv.x, gv.y, gv.z, gv.w};
#pragma unroll
        for (int i = 0; i < 4; ++i)
#pragma unroll
          for (int j = 0; j < 4; ++j) acc[i][j] += a[i] * g[j];
      }
      __syncthreads();
    }
#pragma unroll
    for (int i = 0; i < 4; ++i) {
      int mi = m0 + ty * 4 + i;
      if (mi >= lm) continue;
      int hrow = imx[mi];
#pragma unroll
      for (int j = 0; j < 4; ++j) {
        int col = c0 + tx * 4 + j;
        if (col >= HDIM) continue;
        float y = acc[i][j] + Hc[(size_t)hrow * HDIM + col] + bc[col];
        colsum[j] += y > 0.f ? y : 0.f;
      }
    }
  }
#pragma unroll
  for (int j = 0; j < 4; ++j) Ps[ty][tx * 4 + j] = colsum[j];
  __syncthreads();
  if (tid < 64) {
    float s = 0.f;
#pragma unroll
    for (int r = 0; r < 16; ++r) s += Ps[r][tid];
    int col = c0 + tid;
    if (col < HDIM) outacc[(size_t)b * HDIM + col] = s;
  }
}

// ---------------- K7: classifier head -> out [B,2] -------------------------
__global__ __launch_bounds__(320) void k_cls(
    const float* __restrict__ cr, const float* __restrict__ cc,
    const float* __restrict__ Wcls, const float* __restrict__ bcls,
    const float* __restrict__ Wout, const float* __restrict__ bout,
    float* __restrict__ out) {
  __shared__ __align__(16) float cz[2 * HDIM];
  __shared__ float zz[HDIM];
  int b = blockIdx.x, tid = threadIdx.x;
  if (tid < HDIM) {
    cz[tid] = cr[(size_t)b * HDIM + tid];
    cz[HDIM + tid] = cc[(size_t)b * HDIM + tid];
  }
  __syncthreads();
  if (tid < HDIM) {
    float acc = bcls[tid];
    for (int k4 = 0; k4 < 2 * HDIM; k4 += 4) {
      float4 c = *(const float4*)&cz[k4];
      acc += c.x * Wcls[(size_t)(k4 + 0) * HDIM + tid] +
             c.y * Wcls[(size_t)(k4 + 1) * HDIM + tid] +
             c.z * Wcls[(size_t)(k4 + 2) * HDIM + tid] +
             c.w * Wcls[(size_t)(k4 + 3) * HDIM + tid];
    }
    zz[tid] = acc > 0.f ? acc : 0.f;
  }
  __syncthreads();
  int o = tid >> 6, lane = tid & 63;
  if (o < 2) {
    float p = 0.f;
    for (int j = lane; j < HDIM; j += 64) p += zz[j] * Wout[(size_t)j * 2 + o];
#pragma unroll
    for (int off = 32; off > 0; off >>= 1) p += __shfl_down(p, off, 64);
    if (lane == 0) out[b * 2 + o] = p + bout[o];
  }
}

extern "C" void kernel_launch(void* const* d_in, const int* in_sizes, int n_in,
                              void* d_out, int out_size, void* d_ws, size_t ws_size,
                              hipStream_t stream) {
  (void)in_sizes; (void)n_in; (void)out_size; (void)ws_size;
  const int* data = (const int*)d_in[0];
  const int* row_idx = (const int*)d_in[1];
  const int* col_idx = (const int*)d_in[2];
  const int* row_len = (const int*)d_in[3];
  const int* col_len = (const int*)d_in[4];
  const float* emb = (const float*)d_in[5];
  const float* W1 = (const float*)d_in[6];
  const float* b1 = (const float*)d_in[7];
  const float* W2 = (const float*)d_in[8];
  const float* b2 = (const float*)d_in[9];
  const float* Wc = (const float*)d_in[10];
  const float* bc = (const float*)d_in[11];
  const float* Wcls = (const float*)d_in[12];
  const float* bcls = (const float*)d_in[13];
  const float* Wout = (const float*)d_in[14];
  const float* bout = (const float*)d_in[15];
  float* out = (float*)d_out;

  float* ws = (float*)d_ws;
  size_t off = 0;
  float* enc = ws + off; off += (size_t)NS * DDIM;
  float* h1 = ws + off; off += (size_t)NS * HDIM;
  float* henc = ws + off; off += (size_t)NS * HDIM;
  float* hn = ws + off; off += (size_t)NS * HDIM;
  float* Hc = ws + off; off += (size_t)NS * HDIM;
  float* Hcb = ws + off; off += (size_t)NS * HDIM;
  float* Km = ws + off; off += (size_t)BB * NMAX * MMAX;
  float* cr = ws + off; off += (size_t)BB * HDIM;
  float* cc = ws + off; off += (size_t)BB * HDIM;

  dim3 gNS((NS + 127) / 128, (HDIM + 63) / 64);

  k_embed<<<NS, 256, 0, stream>>>(data, emb, enc);
  k_gemm<<<gNS, 256, 0, stream>>>(enc, W1, b1, h1, NS, HDIM, DDIM, 1);
  k_gemm<<<gNS, 256, 0, stream>>>(h1, W2, b2, henc, NS, HDIM, HDIM, 1);
  k_norm<<<(NS + 3) / 4, 256, 0, stream>>>(henc, hn);
  k_gemm<<<gNS, 256, 0, stream>>>(henc, Wc, nullptr, Hc, NS, HDIM, HDIM, 0);
  k_gemm<<<gNS, 256, 0, stream>>>(henc, Wc + (size_t)HDIM * HDIM, nullptr, Hcb,
                                  NS, HDIM, HDIM, 0);
  k_cost<<<dim3(2, 2, BB), 256, 0, stream>>>(hn, row_idx, col_idx, row_len,
                                             col_len, Km);
  k_sinkhorn<<<BB, 512, 0, stream>>>(Km, row_len, col_len);
  k_att_cmp<0><<<dim3(5, BB), 256, 0, stream>>>(
      Km, Hc, Hcb, row_idx, col_idx, row_len, col_len, bc, cr);
  k_att_cmp<1><<<dim3(5, BB), 256, 0, stream>>>(
      Km, Hc, Hcb, col_idx, row_idx, col_len, row_len, bc, cc);
  k_cls<<<BB, 320, 0, stream>>>(cr, cc, Wcls, bcls, Wout, bout, out);
}

// Round 5
// 695.410 us; speedup vs baseline: 1.1042x; 1.1042x over previous
//
#include <hip/hip_runtime.h>
#include <math.h>

#define NS 10000
#define LSEQ 32
#define DDIM 300
#define HDIM 300
#define BB 256
#define NMAX 128
#define MMAX 128
#define EPSR 0.1f
#define SITERS 50

// ------- K1: embedding + masked mean pool -> enc [NS, D], float4 ----------
__global__ __launch_bounds__(256) void k_embed(const int* __restrict__ data,
                                               const float* __restrict__ emb,
                                               float* __restrict__ enc) {
  __shared__ int ids[LSEQ];
  __shared__ __align__(16) float4 part[3][76];
  int s = blockIdx.x;
  int tid = threadIdx.x;
  if (tid < LSEQ) ids[tid] = data[s * LSEQ + tid];
  __syncthreads();
  int cnt = 0;
#pragma unroll
  for (int t = 0; t < LSEQ; ++t) cnt += (ids[t] != 0) ? 1 : 0;
  int g = tid / 75, d = tid - g * 75;
  const float4* emb4 = (const float4*)emb;
  if (g < 3) {
    float4 acc = make_float4(0.f, 0.f, 0.f, 0.f);
    for (int t = g; t < LSEQ; t += 3) {
      int id = ids[t];
      if (id != 0) {
        float4 e = emb4[(size_t)id * 75 + d];
        acc.x += e.x; acc.y += e.y; acc.z += e.z; acc.w += e.w;
      }
    }
    part[g][d] = acc;
  }
  __syncthreads();
  if (g == 0) {
    float4 a = part[0][d], b = part[1][d], c = part[2][d];
    float inv = 1.f / (float)(cnt > 0 ? cnt : 1);
    float4 r = make_float4((a.x + b.x + c.x) * inv, (a.y + b.y + c.y) * inv,
                           (a.z + b.z + c.z) * inv, (a.w + b.w + c.w) * inv);
    ((float4*)enc)[(size_t)s * 75 + d] = r;
  }
}

// --- K2: f32 GEMM 64x64 tile, 4x4 micro, split-K over 2 block-halves -------
// 512 threads: half = tid>>8 handles k in [half*160, half*160+160) (zero-
// padded past K=300). Halves reduce via LDS overlaid on the staging area.
__global__ __launch_bounds__(512) void k_gemm(
    const float* __restrict__ A, const float* __restrict__ W,
    const float* __restrict__ bias, float* __restrict__ C,
    int M, int N, int K, int relu) {
  __shared__ __align__(16) float smem[2][2][16][68];  // [half][A|W][k][mn]
  float* red = &smem[0][0][0][0];                     // 4096-float overlay
  int tid = threadIdx.x;
  int half = tid >> 8, t = tid & 255, tx = t & 15, ty = t >> 4;
  int m0 = blockIdx.x * 64, n0 = blockIdx.y * 64;
  float acc[4][4] = {};
  int kbase = half * 160;
  for (int c = 0; c < 10; ++c) {
    int k0 = kbase + c * 16;
    for (int l = t; l < 1024; l += 256) {
      int kk = l & 15, mm = l >> 4;
      int m = m0 + mm, k = k0 + kk;
      smem[half][0][kk][mm] = (m < M && k < K) ? A[(size_t)m * K + k] : 0.f;
    }
    for (int l = t; l < 1024; l += 256) {
      int nn = l & 63, kk = l >> 6;
      int n = n0 + nn, k = k0 + kk;
      smem[half][1][kk][nn] = (n < N && k < K) ? W[(size_t)k * N + n] : 0.f;
    }
    __syncthreads();
#pragma unroll
    for (int kk = 0; kk < 16; ++kk) {
      float4 av = *(const float4*)&smem[half][0][kk][ty * 4];
      float4 wv = *(const float4*)&smem[half][1][kk][tx * 4];
      float a[4] = {av.x, av.y, av.z, av.w};
      float w[4] = {wv.x, wv.y, wv.z, wv.w};
#pragma unroll
      for (int i = 0; i < 4; ++i)
#pragma unroll
        for (int j = 0; j < 4; ++j) acc[i][j] += a[i] * w[j];
    }
    __syncthreads();
  }
  // cross-half reduction: half1 deposits, half0 accumulates + epilogue
  if (half == 1) {
#pragma unroll
    for (int i = 0; i < 4; ++i)
#pragma unroll
      for (int j = 0; j < 4; ++j) red[(i * 4 + j) * 256 + t] = acc[i][j];
  }
  __syncthreads();
  if (half == 0) {
#pragma unroll
    for (int i = 0; i < 4; ++i)
#pragma unroll
      for (int j = 0; j < 4; ++j) acc[i][j] += red[(i * 4 + j) * 256 + t];
#pragma unroll
    for (int i = 0; i < 4; ++i) {
      int m = m0 + ty * 4 + i;
      if (m >= M) continue;
      int nb = n0 + tx * 4;
      if (nb + 3 < N) {
        float4 v;
        v.x = acc[i][0] + (bias ? bias[nb + 0] : 0.f);
        v.y = acc[i][1] + (bias ? bias[nb + 1] : 0.f);
        v.z = acc[i][2] + (bias ? bias[nb + 2] : 0.f);
        v.w = acc[i][3] + (bias ? bias[nb + 3] : 0.f);
        if (relu) {
          v.x = v.x > 0.f ? v.x : 0.f; v.y = v.y > 0.f ? v.y : 0.f;
          v.z = v.z > 0.f ? v.z : 0.f; v.w = v.w > 0.f ? v.w : 0.f;
        }
        *(float4*)&C[(size_t)m * N + nb] = v;
      } else {
#pragma unroll
        for (int j = 0; j < 4; ++j) {
          int n = nb + j;
          if (n >= N) continue;
          float v = acc[i][j] + (bias ? bias[n] : 0.f);
          if (relu) v = v > 0.f ? v : 0.f;
          C[(size_t)m * N + n] = v;
        }
      }
    }
  }
}

// ---------------- K3: row-normalize henc -> hn [NS, H] ---------------------
__global__ __launch_bounds__(256) void k_norm(const float* __restrict__ henc,
                                              float* __restrict__ hn) {
  int s = blockIdx.x * 4 + (threadIdx.x >> 6);
  int lane = threadIdx.x & 63;
  if (s >= NS) return;
  const float* src = henc + (size_t)s * HDIM;
  float v[5];
  float ss = 0.f;
#pragma unroll
  for (int q = 0; q < 5; ++q) {
    int d = lane + q * 64;
    v[q] = (d < HDIM) ? src[d] : 0.f;
    ss += v[q] * v[q];
  }
#pragma unroll
  for (int off = 32; off > 0; off >>= 1) ss += __shfl_down(ss, off, 64);
  ss = __shfl(ss, 0, 64);
  float inv = 1.f / (sqrtf(ss) + 1e-8f);
  float* dst = hn + (size_t)s * HDIM;
#pragma unroll
  for (int q = 0; q < 5; ++q) {
    int d = lane + q * 64;
    if (d < HDIM) dst[d] = v[q] * inv;
  }
}

// --- K4: cost as 64x64-tiled GEMM (K=300) w/ gather + fused exp epilogue ---
__global__ __launch_bounds__(256) void k_cost(
    const float* __restrict__ hn, const int* __restrict__ ridx,
    const int* __restrict__ cidx, const int* __restrict__ rlen,
    const int* __restrict__ clen, float* __restrict__ Kmat) {
  int b = blockIdx.z;
  int r0 = blockIdx.x * 64, c0 = blockIdx.y * 64;
  int rl = rlen[b], cl = clen[b];
  float* Kg = Kmat + (size_t)b * NMAX * MMAX;
  int tid = threadIdx.x, tx = tid & 15, ty = tid >> 4;
  if (r0 >= rl || c0 >= cl) {
    for (int l = tid; l < 64 * 16; l += 256) {
      int i = l >> 4, j = (l & 15) << 2;
      *(float4*)&Kg[(size_t)(r0 + i) * MMAX + c0 + j] =
          make_float4(0.f, 0.f, 0.f, 0.f);
    }
    return;
  }
  __shared__ int rix[64], cix[64];
  __shared__ __align__(16) float As[16][68];
  __shared__ __align__(16) float Bs[16][68];
  if (tid < 64) rix[tid] = ridx[b * NMAX + r0 + tid];
  else if (tid < 128) cix[tid - 64] = cidx[b * MMAX + c0 + tid - 64];
  __syncthreads();
  float acc[4][4] = {};
  for (int k0 = 0; k0 < HDIM; k0 += 16) {
    for (int l = tid; l < 1024; l += 256) {
      int kk = l & 15, mm = l >> 4;
      int k = k0 + kk;
      As[kk][mm] = (k < HDIM) ? hn[(size_t)rix[mm] * HDIM + k] : 0.f;
    }
    for (int l = tid; l < 1024; l += 256) {
      int kk = l & 15, mm = l >> 4;
      int k = k0 + kk;
      Bs[kk][mm] = (k < HDIM) ? hn[(size_t)cix[mm] * HDIM + k] : 0.f;
    }
    __syncthreads();
#pragma unroll
    for (int kk = 0; kk < 16; ++kk) {
      float4 av = *(const float4*)&As[kk][ty * 4];
      float4 bv = *(const float4*)&Bs[kk][tx * 4];
      float a[4] = {av.x, av.y, av.z, av.w};
      float w[4] = {bv.x, bv.y, bv.z, bv.w};
#pragma unroll
      for (int i = 0; i < 4; ++i)
#pragma unroll
        for (int j = 0; j < 4; ++j) acc[i][j] += a[i] * w[j];
    }
    __syncthreads();
  }
#pragma unroll
  for (int i = 0; i < 4; ++i) {
    int n = r0 + ty * 4 + i;
    float4 kv;
    float* kvp = &kv.x;
#pragma unroll
    for (int j = 0; j < 4; ++j) {
      int m = c0 + tx * 4 + j;
      kvp[j] = (n < rl && m < cl) ? expf((acc[i][j] - 1.f) / EPSR) : 0.f;
    }
    *(float4*)&Kg[(size_t)n * MMAX + c0 + tx * 4] = kv;
  }
}

// --------- K5: Sinkhorn, K held in VGPRs (kr row / kt col slices) ----------
__global__ __launch_bounds__(512) void k_sinkhorn(
    float* __restrict__ Kmat, const int* __restrict__ rlen,
    const int* __restrict__ clen) {
  __shared__ __align__(16) float vq[4][36];
  __shared__ __align__(16) float uq[4][36];
  int b = blockIdx.x;
  int tid = threadIdx.x;
  int n = tid >> 2, q = tid & 3;
  int rl = rlen[b], cl = clen[b];
  float* Kg = Kmat + (size_t)b * NMAX * MMAX;
  float kr[32], kt[32];
  const float4* Kg4 = (const float4*)(Kg + (size_t)n * MMAX + 32 * q);
#pragma unroll
  for (int t = 0; t < 8; ++t) *(float4*)&kr[4 * t] = Kg4[t];
#pragma unroll
  for (int j = 0; j < 32; ++j) kt[j] = Kg[(size_t)(32 * q + j) * MMAX + n];
  if (tid < 128) vq[tid >> 5][tid & 31] = (tid < cl) ? 1.f : 0.f;
  float av = (n < rl) ? 1.f / (float)rl : 0.f;
  float bv = (n < cl) ? 1.f / (float)cl : 0.f;
  float un = 0.f;
  __syncthreads();
  for (int it = 0; it < SITERS; ++it) {
    float s = 0.f;
#pragma unroll
    for (int t = 0; t < 8; ++t) {
      float4 vv = *(const float4*)&vq[q][4 * t];
      s += kr[4 * t + 0] * vv.x + kr[4 * t + 1] * vv.y +
           kr[4 * t + 2] * vv.z + kr[4 * t + 3] * vv.w;
    }
    s += __shfl_xor(s, 1, 64);
    s += __shfl_xor(s, 2, 64);
    un = (n < rl) ? av / s : 0.f;
    if (q == 0) uq[n >> 5][n & 31] = un;
    __syncthreads();
    float s2 = 0.f;
#pragma unroll
    for (int t = 0; t < 8; ++t) {
      float4 uu = *(const float4*)&uq[q][4 * t];
      s2 += kt[4 * t + 0] * uu.x + kt[4 * t + 1] * uu.y +
            kt[4 * t + 2] * uu.z + kt[4 * t + 3] * uu.w;
    }
    s2 += __shfl_xor(s2, 1, 64);
    s2 += __shfl_xor(s2, 2, 64);
    float vm = (n < cl) ? bv / s2 : 0.f;
    if (q == 0) vq[n >> 5][n & 31] = vm;
    __syncthreads();
  }
  float4* Pg4 = (float4*)(Kg + (size_t)n * MMAX + 32 * q);
#pragma unroll
  for (int t = 0; t < 8; ++t) {
    float4 vv = *(const float4*)&vq[q][4 * t];
    float4 p;
    p.x = un * kr[4 * t + 0] * vv.x;
    p.y = un * kr[4 * t + 1] * vv.y;
    p.z = un * kr[4 * t + 2] * vv.z;
    p.w = un * kr[4 * t + 3] * vv.w;
    Pg4[t] = p;
  }
}

// ---- K6: attend + compare + masked sum; one block per (col-tile, batch) ---
template <int SIDE>
__global__ __launch_bounds__(256) void k_att_cmp(
    const float* __restrict__ P, const float* __restrict__ Hc,
    const float* __restrict__ Hcb, const int* __restrict__ idx_main,
    const int* __restrict__ idx_other, const int* __restrict__ len_main,
    const int* __restrict__ len_other, const float* __restrict__ bc,
    float* __restrict__ outacc) {
  int b = blockIdx.y;
  int c0 = blockIdx.x * 64;
  int lm = len_main[b], lo = len_other[b];
  __shared__ __align__(16) float Ps[16][68];
  __shared__ __align__(16) float Gs[16][68];
  __shared__ int iox[NMAX];
  __shared__ int imx[NMAX];
  int tid = threadIdx.x, tx = tid & 15, ty = tid >> 4;
  if (tid < 128) iox[tid] = idx_other[b * NMAX + tid];
  else imx[tid - 128] = idx_main[b * NMAX + tid - 128];
  __syncthreads();
  const float* Pb = P + (size_t)b * NMAX * MMAX;
  float colsum[4] = {0.f, 0.f, 0.f, 0.f};
  int nkc = (lo + 15) >> 4;  // P is zero beyond lo -> no k-tail masking needed
  for (int m0 = 0; m0 < lm; m0 += 64) {
    float acc[4][4] = {};
    for (int kc = 0; kc < nkc; ++kc) {
      int k0 = kc << 4;
      if (SIDE == 0) {
        for (int l = tid; l < 1024; l += 256) {
          int kk = l & 15, mm = l >> 4;
          Ps[kk][mm] = Pb[(size_t)(m0 + mm) * MMAX + k0 + kk];
        }
      } else {
        for (int l = tid; l < 1024; l += 256) {
          int mm = l & 63, kk = l >> 6;
          Ps[kk][mm] = Pb[(size_t)(k0 + kk) * MMAX + m0 + mm];
        }
      }
      for (int l = tid; l < 1024; l += 256) {
        int jj = l & 63, kk = l >> 6;
        int col = c0 + jj;
        Gs[kk][jj] = (col < HDIM) ? Hcb[(size_t)iox[k0 + kk] * HDIM + col] : 0.f;
      }
      __syncthreads();
#pragma unroll
      for (int kk = 0; kk < 16; ++kk) {
        float4 av = *(const float4*)&Ps[kk][ty * 4];
        float4 gv = *(const float4*)&Gs[kk][tx * 4];
        float a[4] = {av.x, av.y, av.z, av.w};
        float g[4] = {gv.x, gv.y, gv.z, gv.w};
#pragma unroll
        for (int i = 0; i < 4; ++i)
#pragma unroll
          for (int j = 0; j < 4; ++j) acc[i][j] += a[i] * g[j];
      }
      __syncthreads();
    }
#pragma unroll
    for (int i = 0; i < 4; ++i) {
      int mi = m0 + ty * 4 + i;
      if (mi >= lm) continue;
      int hrow = imx[mi];
#pragma unroll
      for (int j = 0; j < 4; ++j) {
        int col = c0 + tx * 4 + j;
        if (col >= HDIM) continue;
        float y = acc[i][j] + Hc[(size_t)hrow * HDIM + col] + bc[col];
        colsum[j] += y > 0.f ? y : 0.f;
      }
    }
  }
#pragma unroll
  for (int j = 0; j < 4; ++j) Ps[ty][tx * 4 + j] = colsum[j];
  __syncthreads();
  if (tid < 64) {
    float s = 0.f;
#pragma unroll
    for (int r = 0; r < 16; ++r) s += Ps[r][tid];
    int col = c0 + tid;
    if (col < HDIM) outacc[(size_t)b * HDIM + col] = s;
  }
}

// ---------------- K7: classifier head -> out [B,2] -------------------------
__global__ __launch_bounds__(320) void k_cls(
    const float* __restrict__ cr, const float* __restrict__ cc,
    const float* __restrict__ Wcls, const float* __restrict__ bcls,
    const float* __restrict__ Wout, const float* __restrict__ bout,
    float* __restrict__ out) {
  __shared__ __align__(16) float cz[2 * HDIM];
  __shared__ float zz[HDIM];
  int b = blockIdx.x, tid = threadIdx.x;
  if (tid < HDIM) {
    cz[tid] = cr[(size_t)b * HDIM + tid];
    cz[HDIM + tid] = cc[(size_t)b * HDIM + tid];
  }
  __syncthreads();
  if (tid < HDIM) {
    float acc = bcls[tid];
    for (int k4 = 0; k4 < 2 * HDIM; k4 += 4) {
      float4 c = *(const float4*)&cz[k4];
      acc += c.x * Wcls[(size_t)(k4 + 0) * HDIM + tid] +
             c.y * Wcls[(size_t)(k4 + 1) * HDIM + tid] +
             c.z * Wcls[(size_t)(k4 + 2) * HDIM + tid] +
             c.w * Wcls[(size_t)(k4 + 3) * HDIM + tid];
    }
    zz[tid] = acc > 0.f ? acc : 0.f;
  }
  __syncthreads();
  int o = tid >> 6, lane = tid & 63;
  if (o < 2) {
    float p = 0.f;
    for (int j = lane; j < HDIM; j += 64) p += zz[j] * Wout[(size_t)j * 2 + o];
#pragma unroll
    for (int off = 32; off > 0; off >>= 1) p += __shfl_down(p, off, 64);
    if (lane == 0) out[b * 2 + o] = p + bout[o];
  }
}

extern "C" void kernel_launch(void* const* d_in, const int* in_sizes, int n_in,
                              void* d_out, int out_size, void* d_ws, size_t ws_size,
                              hipStream_t stream) {
  (void)in_sizes; (void)n_in; (void)out_size; (void)ws_size;
  const int* data = (const int*)d_in[0];
  const int* row_idx = (const int*)d_in[1];
  const int* col_idx = (const int*)d_in[2];
  const int* row_len = (const int*)d_in[3];
  const int* col_len = (const int*)d_in[4];
  const float* emb = (const float*)d_in[5];
  const float* W1 = (const float*)d_in[6];
  const float* b1 = (const float*)d_in[7];
  const float* W2 = (const float*)d_in[8];
  const float* b2 = (const float*)d_in[9];
  const float* Wc = (const float*)d_in[10];
  const float* bc = (const float*)d_in[11];
  const float* Wcls = (const float*)d_in[12];
  const float* bcls = (const float*)d_in[13];
  const float* Wout = (const float*)d_in[14];
  const float* bout = (const float*)d_in[15];
  float* out = (float*)d_out;

  float* ws = (float*)d_ws;
  size_t off = 0;
  float* enc = ws + off; off += (size_t)NS * DDIM;
  float* h1 = ws + off; off += (size_t)NS * HDIM;
  float* henc = ws + off; off += (size_t)NS * HDIM;
  float* hn = ws + off; off += (size_t)NS * HDIM;
  float* Hc = ws + off; off += (size_t)NS * HDIM;
  float* Hcb = ws + off; off += (size_t)NS * HDIM;
  float* Km = ws + off; off += (size_t)BB * NMAX * MMAX;
  float* cr = ws + off; off += (size_t)BB * HDIM;
  float* cc = ws + off; off += (size_t)BB * HDIM;

  dim3 gNS((NS + 63) / 64, (HDIM + 63) / 64);

  k_embed<<<NS, 256, 0, stream>>>(data, emb, enc);
  k_gemm<<<gNS, 512, 0, stream>>>(enc, W1, b1, h1, NS, HDIM, DDIM, 1);
  k_gemm<<<gNS, 512, 0, stream>>>(h1, W2, b2, henc, NS, HDIM, HDIM, 1);
  k_norm<<<(NS + 3) / 4, 256, 0, stream>>>(henc, hn);
  k_gemm<<<gNS, 512, 0, stream>>>(henc, Wc, nullptr, Hc, NS, HDIM, HDIM, 0);
  k_gemm<<<gNS, 512, 0, stream>>>(henc, Wc + (size_t)HDIM * HDIM, nullptr, Hcb,
                                  NS, HDIM, HDIM, 0);
  k_cost<<<dim3(2, 2, BB), 256, 0, stream>>>(hn, row_idx, col_idx, row_len,
                                             col_len, Km);
  k_sinkhorn<<<BB, 512, 0, stream>>>(Km, row_len, col_len);
  k_att_cmp<0><<<dim3(5, BB), 256, 0, stream>>>(
      Km, Hc, Hcb, row_idx, col_idx, row_len, col_len, bc, cr);
  k_att_cmp<1><<<dim3(5, BB), 256, 0, stream>>>(
      Km, Hc, Hcb, col_idx, row_idx, col_len, row_len, bc, cc);
  k_cls<<<BB, 320, 0, stream>>>(cr, cc, Wcls, bcls, Wout, bout, out);
}

// Round 6
// 551.030 us; speedup vs baseline: 1.3935x; 1.2620x over previous
//
#include <hip/hip_runtime.h>
#include <math.h>

#define NS 10000
#define LSEQ 32
#define DDIM 300
#define HDIM 300
#define BB 256
#define NMAX 128
#define MMAX 128
#define EPSR 0.1f
#define SITERS 50

// ------- K1: embedding + masked mean pool -> enc [NS, D], float4 ----------
__global__ __launch_bounds__(256) void k_embed(const int* __restrict__ data,
                                               const float* __restrict__ emb,
                                               float* __restrict__ enc) {
  __shared__ int ids[LSEQ];
  __shared__ __align__(16) float4 part[3][76];
  int s = blockIdx.x;
  int tid = threadIdx.x;
  if (tid < LSEQ) ids[tid] = data[s * LSEQ + tid];
  __syncthreads();
  int cnt = 0;
#pragma unroll
  for (int t = 0; t < LSEQ; ++t) cnt += (ids[t] != 0) ? 1 : 0;
  int g = tid / 75, d = tid - g * 75;
  const float4* emb4 = (const float4*)emb;
  if (g < 3) {
    float4 acc = make_float4(0.f, 0.f, 0.f, 0.f);
    for (int t = g; t < LSEQ; t += 3) {
      int id = ids[t];
      if (id != 0) {
        float4 e = emb4[(size_t)id * 75 + d];
        acc.x += e.x; acc.y += e.y; acc.z += e.z; acc.w += e.w;
      }
    }
    part[g][d] = acc;
  }
  __syncthreads();
  if (g == 0) {
    float4 a = part[0][d], b = part[1][d], c = part[2][d];
    float inv = 1.f / (float)(cnt > 0 ? cnt : 1);
    float4 r = make_float4((a.x + b.x + c.x) * inv, (a.y + b.y + c.y) * inv,
                           (a.z + b.z + c.z) * inv, (a.w + b.w + c.w) * inv);
    ((float4*)enc)[(size_t)s * 75 + d] = r;
  }
}

// --- K2: f32 GEMM 64x64, 4x4 micro, split-K halves + reg-prefetch dbuf -----
// 512 threads: half owns k in [half*160, half*160+160). Double-buffered LDS,
// one barrier per chunk; chunk c+1 loads issue during chunk c compute.
__global__ __launch_bounds__(512) void k_gemm(
    const float* __restrict__ A, const float* __restrict__ W,
    const float* __restrict__ bias, float* __restrict__ C,
    int M, int N, int K, int relu) {
  __shared__ __align__(16) float smem[2][2][2][16][68];  // [buf][half][A|W]
  float* red = &smem[0][0][0][0][0];                     // 4096-float overlay
  int tid = threadIdx.x;
  int half = tid >> 8, t = tid & 255, tx = t & 15, ty = t >> 4;
  int m0 = blockIdx.x * 64, n0 = blockIdx.y * 64;
  int kbase = half * 160;
  int kkA = t & 15;   // A: k offset within chunk (constant per thread)
  int kwB = t >> 6;   // W: k offset base (p adds 4)
  int nnW = t & 63;   // W: n offset (constant)
  const float* aB[4]; bool mok[4];
#pragma unroll
  for (int p = 0; p < 4; ++p) {
    int m = m0 + ty + p * 16;
    mok[p] = m < M;
    aB[p] = A + (size_t)m * K + kbase + kkA;
  }
  bool nok = (n0 + nnW) < N;
  const float* wB = W + (size_t)(kbase + kwB) * N + n0 + nnW;
  float aR[4], wR[4];
  float acc[4][4] = {};
  auto loadC = [&](int c) {
    int o = c * 16;
    bool kaok = (kbase + o + kkA) < K;
#pragma unroll
    for (int p = 0; p < 4; ++p) aR[p] = (mok[p] && kaok) ? aB[p][o] : 0.f;
#pragma unroll
    for (int p = 0; p < 4; ++p) {
      bool kwok = (kbase + o + kwB + p * 4) < K;
      wR[p] = (nok && kwok) ? wB[(size_t)(o + p * 4) * N] : 0.f;
    }
  };
  auto storeC = [&](int buf) {
#pragma unroll
    for (int p = 0; p < 4; ++p) smem[buf][half][0][kkA][ty + p * 16] = aR[p];
#pragma unroll
    for (int p = 0; p < 4; ++p) smem[buf][half][1][kwB + p * 4][nnW] = wR[p];
  };
  loadC(0);
  storeC(0);
  __syncthreads();
  int cur = 0;
  for (int c = 0; c < 10; ++c) {
    if (c < 9) loadC(c + 1);
#pragma unroll
    for (int kk = 0; kk < 16; ++kk) {
      float4 av = *(const float4*)&smem[cur][half][0][kk][ty * 4];
      float4 wv = *(const float4*)&smem[cur][half][1][kk][tx * 4];
      float a[4] = {av.x, av.y, av.z, av.w};
      float w[4] = {wv.x, wv.y, wv.z, wv.w};
#pragma unroll
      for (int i = 0; i < 4; ++i)
#pragma unroll
        for (int j = 0; j < 4; ++j) acc[i][j] += a[i] * w[j];
    }
    if (c < 9) storeC(cur ^ 1);
    __syncthreads();
    cur ^= 1;
  }
  // cross-half reduction: half1 deposits, half0 accumulates + epilogue
  if (half == 1) {
#pragma unroll
    for (int i = 0; i < 4; ++i)
#pragma unroll
      for (int j = 0; j < 4; ++j) red[(i * 4 + j) * 256 + t] = acc[i][j];
  }
  __syncthreads();
  if (half == 0) {
#pragma unroll
    for (int i = 0; i < 4; ++i)
#pragma unroll
      for (int j = 0; j < 4; ++j) acc[i][j] += red[(i * 4 + j) * 256 + t];
#pragma unroll
    for (int i = 0; i < 4; ++i) {
      int m = m0 + ty * 4 + i;
      if (m >= M) continue;
      int nb = n0 + tx * 4;
      if (nb + 3 < N) {
        float4 v;
        v.x = acc[i][0] + (bias ? bias[nb + 0] : 0.f);
        v.y = acc[i][1] + (bias ? bias[nb + 1] : 0.f);
        v.z = acc[i][2] + (bias ? bias[nb + 2] : 0.f);
        v.w = acc[i][3] + (bias ? bias[nb + 3] : 0.f);
        if (relu) {
          v.x = v.x > 0.f ? v.x : 0.f; v.y = v.y > 0.f ? v.y : 0.f;
          v.z = v.z > 0.f ? v.z : 0.f; v.w = v.w > 0.f ? v.w : 0.f;
        }
        *(float4*)&C[(size_t)m * N + nb] = v;
      } else {
#pragma unroll
        for (int j = 0; j < 4; ++j) {
          int n = nb + j;
          if (n >= N) continue;
          float v = acc[i][j] + (bias ? bias[n] : 0.f);
          if (relu) v = v > 0.f ? v : 0.f;
          C[(size_t)m * N + n] = v;
        }
      }
    }
  }
}

// ---------------- K3: inverse row norms of henc -> rinv [NS] ---------------
__global__ __launch_bounds__(256) void k_rnorm(const float* __restrict__ henc,
                                               float* __restrict__ rinv) {
  int s = blockIdx.x * 4 + (threadIdx.x >> 6);
  int lane = threadIdx.x & 63;
  if (s >= NS) return;
  const float* src = henc + (size_t)s * HDIM;
  float ss = 0.f;
#pragma unroll
  for (int q = 0; q < 5; ++q) {
    int d = lane + q * 64;
    float x = (d < HDIM) ? src[d] : 0.f;
    ss += x * x;
  }
#pragma unroll
  for (int off = 32; off > 0; off >>= 1) ss += __shfl_down(ss, off, 64);
  if (lane == 0) rinv[s] = 1.f / (sqrtf(ss) + 1e-8f);
}

// ---------------- K4: Wcat[k][j] = [Wc_top | Wc_bot] column-concat ---------
__global__ void k_wcat(const float* __restrict__ Wc, float* __restrict__ Wcat) {
  int i = blockIdx.x * 256 + threadIdx.x;
  if (i >= HDIM * 2 * HDIM) return;
  int k = i / (2 * HDIM), j = i - k * 2 * HDIM;
  Wcat[i] = (j < HDIM) ? Wc[(size_t)k * HDIM + j]
                       : Wc[(size_t)(HDIM + k) * HDIM + (j - HDIM)];
}

// --- K5: cost GEMM (gather + on-the-fly normalize) + exp, prefetch dbuf ----
__global__ __launch_bounds__(256) void k_cost(
    const float* __restrict__ henc, const float* __restrict__ rinv,
    const int* __restrict__ ridx, const int* __restrict__ cidx,
    const int* __restrict__ rlen, const int* __restrict__ clen,
    float* __restrict__ Kmat) {
  int b = blockIdx.z;
  int r0 = blockIdx.x * 64, c0 = blockIdx.y * 64;
  int rl = rlen[b], cl = clen[b];
  float* Kg = Kmat + (size_t)b * NMAX * MMAX;
  int tid = threadIdx.x, tx = tid & 15, ty = tid >> 4;
  if (r0 >= rl || c0 >= cl) {
    for (int l = tid; l < 64 * 16; l += 256) {
      int i = l >> 4, j = (l & 15) << 2;
      *(float4*)&Kg[(size_t)(r0 + i) * MMAX + c0 + j] =
          make_float4(0.f, 0.f, 0.f, 0.f);
    }
    return;
  }
  __shared__ int rix[64], cix[64];
  __shared__ float rnv[64], cnv[64];
  __shared__ __align__(16) float smem[2][2][16][68];
  if (tid < 64) {
    int r = ridx[b * NMAX + r0 + tid];
    rix[tid] = r; rnv[tid] = rinv[r];
  } else if (tid < 128) {
    int r = cidx[b * MMAX + c0 + tid - 64];
    cix[tid - 64] = r; cnv[tid - 64] = rinv[r];
  }
  __syncthreads();
  const float* aP[4]; const float* bP[4];
  float aS[4], bS[4];
#pragma unroll
  for (int p = 0; p < 4; ++p) {
    int mm = ty + p * 16;
    aP[p] = henc + (size_t)rix[mm] * HDIM + tx; aS[p] = rnv[mm];
    bP[p] = henc + (size_t)cix[mm] * HDIM + tx; bS[p] = cnv[mm];
  }
  float aR[4], bR[4];
  auto loadC = [&](int c) {
    int o = c * 16;
    bool ok = (o + tx) < HDIM;
#pragma unroll
    for (int p = 0; p < 4; ++p) aR[p] = ok ? aP[p][o] * aS[p] : 0.f;
#pragma unroll
    for (int p = 0; p < 4; ++p) bR[p] = ok ? bP[p][o] * bS[p] : 0.f;
  };
  auto storeC = [&](int buf) {
#pragma unroll
    for (int p = 0; p < 4; ++p) smem[buf][0][tx][ty + p * 16] = aR[p];
#pragma unroll
    for (int p = 0; p < 4; ++p) smem[buf][1][tx][ty + p * 16] = bR[p];
  };
  float acc[4][4] = {};
  loadC(0);
  storeC(0);
  __syncthreads();
  int cur = 0;
  const int NCH = (HDIM + 15) / 16;  // 19
  for (int c = 0; c < NCH; ++c) {
    if (c + 1 < NCH) loadC(c + 1);
#pragma unroll
    for (int kk = 0; kk < 16; ++kk) {
      float4 av = *(const float4*)&smem[cur][0][kk][ty * 4];
      float4 bv = *(const float4*)&smem[cur][1][kk][tx * 4];
      float a[4] = {av.x, av.y, av.z, av.w};
      float w[4] = {bv.x, bv.y, bv.z, bv.w};
#pragma unroll
      for (int i = 0; i < 4; ++i)
#pragma unroll
        for (int j = 0; j < 4; ++j) acc[i][j] += a[i] * w[j];
    }
    if (c + 1 < NCH) storeC(cur ^ 1);
    __syncthreads();
    cur ^= 1;
  }
#pragma unroll
  for (int i = 0; i < 4; ++i) {
    int n = r0 + ty * 4 + i;
    float4 kv;
    float* kvp = &kv.x;
#pragma unroll
    for (int j = 0; j < 4; ++j) {
      int m = c0 + tx * 4 + j;
      kvp[j] = (n < rl && m < cl) ? expf((acc[i][j] - 1.f) / EPSR) : 0.f;
    }
    *(float4*)&Kg[(size_t)n * MMAX + c0 + tx * 4] = kv;
  }
}

// --------- K6: Sinkhorn, K held in VGPRs (kr row / kt col slices) ----------
__global__ __launch_bounds__(512) void k_sinkhorn(
    float* __restrict__ Kmat, const int* __restrict__ rlen,
    const int* __restrict__ clen) {
  __shared__ __align__(16) float vq[4][36];
  __shared__ __align__(16) float uq[4][36];
  int b = blockIdx.x;
  int tid = threadIdx.x;
  int n = tid >> 2, q = tid & 3;
  int rl = rlen[b], cl = clen[b];
  float* Kg = Kmat + (size_t)b * NMAX * MMAX;
  float kr[32], kt[32];
  const float4* Kg4 = (const float4*)(Kg + (size_t)n * MMAX + 32 * q);
#pragma unroll
  for (int t = 0; t < 8; ++t) *(float4*)&kr[4 * t] = Kg4[t];
#pragma unroll
  for (int j = 0; j < 32; ++j) kt[j] = Kg[(size_t)(32 * q + j) * MMAX + n];
  if (tid < 128) vq[tid >> 5][tid & 31] = (tid < cl) ? 1.f : 0.f;
  float av = (n < rl) ? 1.f / (float)rl : 0.f;
  float bv = (n < cl) ? 1.f / (float)cl : 0.f;
  float un = 0.f;
  __syncthreads();
  for (int it = 0; it < SITERS; ++it) {
    float s = 0.f;
#pragma unroll
    for (int t = 0; t < 8; ++t) {
      float4 vv = *(const float4*)&vq[q][4 * t];
      s += kr[4 * t + 0] * vv.x + kr[4 * t + 1] * vv.y +
           kr[4 * t + 2] * vv.z + kr[4 * t + 3] * vv.w;
    }
    s += __shfl_xor(s, 1, 64);
    s += __shfl_xor(s, 2, 64);
    un = (n < rl) ? av / s : 0.f;
    if (q == 0) uq[n >> 5][n & 31] = un;
    __syncthreads();
    float s2 = 0.f;
#pragma unroll
    for (int t = 0; t < 8; ++t) {
      float4 uu = *(const float4*)&uq[q][4 * t];
      s2 += kt[4 * t + 0] * uu.x + kt[4 * t + 1] * uu.y +
            kt[4 * t + 2] * uu.z + kt[4 * t + 3] * uu.w;
    }
    s2 += __shfl_xor(s2, 1, 64);
    s2 += __shfl_xor(s2, 2, 64);
    float vm = (n < cl) ? bv / s2 : 0.f;
    if (q == 0) vq[n >> 5][n & 31] = vm;
    __syncthreads();
  }
  float4* Pg4 = (float4*)(Kg + (size_t)n * MMAX + 32 * q);
#pragma unroll
  for (int t = 0; t < 8; ++t) {
    float4 vv = *(const float4*)&vq[q][4 * t];
    float4 p;
    p.x = un * kr[4 * t + 0] * vv.x;
    p.y = un * kr[4 * t + 1] * vv.y;
    p.z = un * kr[4 * t + 2] * vv.z;
    p.w = un * kr[4 * t + 3] * vv.w;
    Pg4[t] = p;
  }
}

// ---- K7: attend + compare + masked sum, prefetch dbuf ---------------------
// HcB: [NS,600] = [Hc | Hcb]. main side adds HcB[.,0:300], other gathers
// HcB[.,300:600]. SIDE 0: P[i][k]; SIDE 1: P[k][j] transposed.
template <int SIDE>
__global__ __launch_bounds__(256) void k_att_cmp(
    const float* __restrict__ P, const float* __restrict__ HcB,
    const int* __restrict__ idx_main, const int* __restrict__ idx_other,
    const int* __restrict__ len_main, const int* __restrict__ len_other,
    const float* __restrict__ bc, float* __restrict__ outacc) {
  int b = blockIdx.y;
  int c0 = blockIdx.x * 64;
  int lm = len_main[b], lo = len_other[b];
  __shared__ __align__(16) float smem[2][2][16][68];  // [buf][P|G]
  __shared__ int iox[NMAX];
  __shared__ int imx[NMAX];
  int tid = threadIdx.x, tx = tid & 15, ty = tid >> 4;
  int jj = tid & 63, kq = tid >> 6;
  if (tid < 128) iox[tid] = idx_other[b * NMAX + tid];
  else imx[tid - 128] = idx_main[b * NMAX + tid - 128];
  __syncthreads();
  const float* Pb = P + (size_t)b * NMAX * MMAX;
  bool cok = (c0 + jj) < HDIM;
  int nkc = (lo + 15) >> 4;
  int nmt = (lm + 63) >> 6;
  float pR[4], gR[4];
  auto loadPG = [&](int mt, int kc) {
    int m0 = mt * 64, k0 = kc * 16;
    if (SIDE == 0) {
#pragma unroll
      for (int p = 0; p < 4; ++p)
        pR[p] = Pb[(size_t)(m0 + ty + p * 16) * MMAX + k0 + tx];
    } else {
#pragma unroll
      for (int p = 0; p < 4; ++p)
        pR[p] = Pb[(size_t)(k0 + kq + p * 4) * MMAX + m0 + jj];
    }
#pragma unroll
    for (int p = 0; p < 4; ++p) {
      int row = iox[k0 + kq + p * 4];
      gR[p] = cok ? HcB[(size_t)row * 600 + 300 + c0 + jj] : 0.f;
    }
  };
  auto storePG = [&](int buf) {
    if (SIDE == 0) {
#pragma unroll
      for (int p = 0; p < 4; ++p) smem[buf][0][tx][ty + p * 16] = pR[p];
    } else {
#pragma unroll
      for (int p = 0; p < 4; ++p) smem[buf][0][kq + p * 4][jj] = pR[p];
    }
#pragma unroll
    for (int p = 0; p < 4; ++p) smem[buf][1][kq + p * 4][jj] = gR[p];
  };
  float colsum[4] = {0.f, 0.f, 0.f, 0.f};
  loadPG(0, 0);
  storePG(0);
  __syncthreads();
  int cur = 0;
  for (int mt = 0; mt < nmt; ++mt) {
    float acc[4][4] = {};
    for (int kc = 0; kc < nkc; ++kc) {
      bool last = (mt == nmt - 1) && (kc == nkc - 1);
      if (!last) {
        int nm = (kc + 1 < nkc) ? mt : mt + 1;
        int nk = (kc + 1 < nkc) ? kc + 1 : 0;
        loadPG(nm, nk);
      }
#pragma unroll
      for (int kk = 0; kk < 16; ++kk) {
        float4 av = *(const float4*)&smem[cur][0][kk][ty * 4];
        float4 gv = *(const float4*)&smem[cur][1][kk][tx * 4];
        float a[4] = {av.x, av.y, av.z, av.w};
        float g[4] = {gv.x, gv.y, gv.z, gv.w};
#pragma unroll
        for (int i = 0; i < 4; ++i)
#pragma unroll
          for (int j = 0; j < 4; ++j) acc[i][j] += a[i] * g[j];
      }
      if (!last) storePG(cur ^ 1);
      __syncthreads();
      cur ^= 1;
    }
    // epilogue for this m-tile (registers + global only — pipeline-safe)
#pragma unroll
    for (int i = 0; i < 4; ++i) {
      int mi = mt * 64 + ty * 4 + i;
      if (mi >= lm) continue;
      int hrow = imx[mi];
#pragma unroll
      for (int j = 0; j < 4; ++j) {
        int col = c0 + tx * 4 + j;
        if (col >= HDIM) continue;
        float y = acc[i][j] + HcB[(size_t)hrow * 600 + col] + bc[col];
        colsum[j] += y > 0.f ? y : 0.f;
      }
    }
  }
  __syncthreads();
  float(*red)[68] = (float(*)[68]) & smem[0][0][0][0];
#pragma unroll
  for (int j = 0; j < 4; ++j) red[ty][tx * 4 + j] = colsum[j];
  __syncthreads();
  if (tid < 64) {
    float s = 0.f;
#pragma unroll
    for (int r = 0; r < 16; ++r) s += red[r][tid];
    int col = c0 + tid;
    if (col < HDIM) outacc[(size_t)b * HDIM + col] = s;
  }
}

// ---------------- K8: classifier head -> out [B,2] -------------------------
__global__ __launch_bounds__(320) void k_cls(
    const float* __restrict__ cr, const float* __restrict__ cc,
    const float* __restrict__ Wcls, const float* __restrict__ bcls,
    const float* __restrict__ Wout, const float* __restrict__ bout,
    float* __restrict__ out) {
  __shared__ __align__(16) float cz[2 * HDIM];
  __shared__ float zz[HDIM];
  int b = blockIdx.x, tid = threadIdx.x;
  if (tid < HDIM) {
    cz[tid] = cr[(size_t)b * HDIM + tid];
    cz[HDIM + tid] = cc[(size_t)b * HDIM + tid];
  }
  __syncthreads();
  if (tid < HDIM) {
    float acc = bcls[tid];
    for (int k4 = 0; k4 < 2 * HDIM; k4 += 4) {
      float4 c = *(const float4*)&cz[k4];
      acc += c.x * Wcls[(size_t)(k4 + 0) * HDIM + tid] +
             c.y * Wcls[(size_t)(k4 + 1) * HDIM + tid] +
             c.z * Wcls[(size_t)(k4 + 2) * HDIM + tid] +
             c.w * Wcls[(size_t)(k4 + 3) * HDIM + tid];
    }
    zz[tid] = acc > 0.f ? acc : 0.f;
  }
  __syncthreads();
  int o = tid >> 6, lane = tid & 63;
  if (o < 2) {
    float p = 0.f;
    for (int j = lane; j < HDIM; j += 64) p += zz[j] * Wout[(size_t)j * 2 + o];
#pragma unroll
    for (int off = 32; off > 0; off >>= 1) p += __shfl_down(p, off, 64);
    if (lane == 0) out[b * 2 + o] = p + bout[o];
  }
}

extern "C" void kernel_launch(void* const* d_in, const int* in_sizes, int n_in,
                              void* d_out, int out_size, void* d_ws, size_t ws_size,
                              hipStream_t stream) {
  (void)in_sizes; (void)n_in; (void)out_size; (void)ws_size;
  const int* data = (const int*)d_in[0];
  const int* row_idx = (const int*)d_in[1];
  const int* col_idx = (const int*)d_in[2];
  const int* row_len = (const int*)d_in[3];
  const int* col_len = (const int*)d_in[4];
  const float* emb = (const float*)d_in[5];
  const float* W1 = (const float*)d_in[6];
  const float* b1 = (const float*)d_in[7];
  const float* W2 = (const float*)d_in[8];
  const float* b2 = (const float*)d_in[9];
  const float* Wc = (const float*)d_in[10];
  const float* bc = (const float*)d_in[11];
  const float* Wcls = (const float*)d_in[12];
  const float* bcls = (const float*)d_in[13];
  const float* Wout = (const float*)d_in[14];
  const float* bout = (const float*)d_in[15];
  float* out = (float*)d_out;

  float* ws = (float*)d_ws;
  size_t off = 0;
  float* enc = ws + off; off += (size_t)NS * DDIM;
  float* h1 = ws + off; off += (size_t)NS * HDIM;
  float* henc = ws + off; off += (size_t)NS * HDIM;
  float* rinv = ws + off; off += NS;
  float* Wcat = ws + off; off += (size_t)HDIM * 2 * HDIM;
  float* HcB = ws + off; off += (size_t)NS * 2 * HDIM;
  float* Km = ws + off; off += (size_t)BB * NMAX * MMAX;
  float* cr = ws + off; off += (size_t)BB * HDIM;
  float* cc = ws + off; off += (size_t)BB * HDIM;

  dim3 gNS((NS + 63) / 64, (HDIM + 63) / 64);
  dim3 gNS6((NS + 63) / 64, (2 * HDIM + 63) / 64);

  k_embed<<<NS, 256, 0, stream>>>(data, emb, enc);
  k_wcat<<<(HDIM * 2 * HDIM + 255) / 256, 256, 0, stream>>>(Wc, Wcat);
  k_gemm<<<gNS, 512, 0, stream>>>(enc, W1, b1, h1, NS, HDIM, DDIM, 1);
  k_gemm<<<gNS, 512, 0, stream>>>(h1, W2, b2, henc, NS, HDIM, HDIM, 1);
  k_rnorm<<<(NS + 3) / 4, 256, 0, stream>>>(henc, rinv);
  k_gemm<<<gNS6, 512, 0, stream>>>(henc, Wcat, nullptr, HcB, NS, 2 * HDIM,
                                   HDIM, 0);
  k_cost<<<dim3(2, 2, BB), 256, 0, stream>>>(henc, rinv, row_idx, col_idx,
                                             row_len, col_len, Km);
  k_sinkhorn<<<BB, 512, 0, stream>>>(Km, row_len, col_len);
  k_att_cmp<0><<<dim3(5, BB), 256, 0, stream>>>(
      Km, HcB, row_idx, col_idx, row_len, col_len, bc, cr);
  k_att_cmp<1><<<dim3(5, BB), 256, 0, stream>>>(
      Km, HcB, col_idx, row_idx, col_len, row_len, bc, cc);
  k_cls<<<BB, 320, 0, stream>>>(cr, cc, Wcls, bcls, Wout, bout, out);
}

// Round 7
// 513.207 us; speedup vs baseline: 1.4962x; 1.0737x over previous
//
#include <hip/hip_runtime.h>
#include <math.h>

#define NS 10000
#define LSEQ 32
#define DDIM 300
#define HDIM 300
#define BB 256
#define NMAX 128
#define MMAX 128
#define EPSR 0.1f
#define SITERS 50

// ------- K1: embedding + masked mean pool -> enc [NS, D], float4 ----------
__global__ __launch_bounds__(256) void k_embed(const int* __restrict__ data,
                                               const float* __restrict__ emb,
                                               float* __restrict__ enc) {
  __shared__ int ids[LSEQ];
  __shared__ __align__(16) float4 part[3][76];
  int s = blockIdx.x;
  int tid = threadIdx.x;
  if (tid < LSEQ) ids[tid] = data[s * LSEQ + tid];
  __syncthreads();
  int cnt = 0;
#pragma unroll
  for (int t = 0; t < LSEQ; ++t) cnt += (ids[t] != 0) ? 1 : 0;
  int g = tid / 75, d = tid - g * 75;
  const float4* emb4 = (const float4*)emb;
  if (g < 3) {
    float4 acc = make_float4(0.f, 0.f, 0.f, 0.f);
    for (int t = g; t < LSEQ; t += 3) {
      int id = ids[t];
      if (id != 0) {
        float4 e = emb4[(size_t)id * 75 + d];
        acc.x += e.x; acc.y += e.y; acc.z += e.z; acc.w += e.w;
      }
    }
    part[g][d] = acc;
  }
  __syncthreads();
  if (g == 0) {
    float4 a = part[0][d], b = part[1][d], c = part[2][d];
    float inv = 1.f / (float)(cnt > 0 ? cnt : 1);
    float4 r = make_float4((a.x + b.x + c.x) * inv, (a.y + b.y + c.y) * inv,
                           (a.z + b.z + c.z) * inv, (a.w + b.w + c.w) * inv);
    ((float4*)enc)[(size_t)s * 75 + d] = r;
  }
}

// --- K2: f32 GEMM 64x64, 4x4 micro, split-K halves + reg-prefetch dbuf -----
// 512 threads: half owns k in [half*160, half*160+160). Double-buffered LDS,
// one barrier per chunk; chunk c+1 loads issue during chunk c compute.
__global__ __launch_bounds__(512) void k_gemm(
    const float* __restrict__ A, const float* __restrict__ W,
    const float* __restrict__ bias, float* __restrict__ C,
    int M, int N, int K, int relu) {
  __shared__ __align__(16) float smem[2][2][2][16][68];  // [buf][half][A|W]
  float* red = &smem[0][0][0][0][0];                     // 4096-float overlay
  int tid = threadIdx.x;
  int half = tid >> 8, t = tid & 255, tx = t & 15, ty = t >> 4;
  int m0 = blockIdx.x * 64, n0 = blockIdx.y * 64;
  int kbase = half * 160;
  int kkA = t & 15;   // A: k offset within chunk (constant per thread)
  int kwB = t >> 6;   // W: k offset base (p adds 4)
  int nnW = t & 63;   // W: n offset (constant)
  const float* aB[4]; bool mok[4];
#pragma unroll
  for (int p = 0; p < 4; ++p) {
    int m = m0 + ty + p * 16;
    mok[p] = m < M;
    aB[p] = A + (size_t)m * K + kbase + kkA;
  }
  bool nok = (n0 + nnW) < N;
  const float* wB = W + (size_t)(kbase + kwB) * N + n0 + nnW;
  float aR[4], wR[4];
  float acc[4][4] = {};
  auto loadC = [&](int c) {
    int o = c * 16;
    bool kaok = (kbase + o + kkA) < K;
#pragma unroll
    for (int p = 0; p < 4; ++p) aR[p] = (mok[p] && kaok) ? aB[p][o] : 0.f;
#pragma unroll
    for (int p = 0; p < 4; ++p) {
      bool kwok = (kbase + o + kwB + p * 4) < K;
      wR[p] = (nok && kwok) ? wB[(size_t)(o + p * 4) * N] : 0.f;
    }
  };
  auto storeC = [&](int buf) {
#pragma unroll
    for (int p = 0; p < 4; ++p) smem[buf][half][0][kkA][ty + p * 16] = aR[p];
#pragma unroll
    for (int p = 0; p < 4; ++p) smem[buf][half][1][kwB + p * 4][nnW] = wR[p];
  };
  loadC(0);
  storeC(0);
  __syncthreads();
  int cur = 0;
  for (int c = 0; c < 10; ++c) {
    if (c < 9) loadC(c + 1);
#pragma unroll
    for (int kk = 0; kk < 16; ++kk) {
      float4 av = *(const float4*)&smem[cur][half][0][kk][ty * 4];
      float4 wv = *(const float4*)&smem[cur][half][1][kk][tx * 4];
      float a[4] = {av.x, av.y, av.z, av.w};
      float w[4] = {wv.x, wv.y, wv.z, wv.w};
#pragma unroll
      for (int i = 0; i < 4; ++i)
#pragma unroll
        for (int j = 0; j < 4; ++j) acc[i][j] += a[i] * w[j];
    }
    if (c < 9) storeC(cur ^ 1);
    __syncthreads();
    cur ^= 1;
  }
  // cross-half reduction: half1 deposits, half0 accumulates + epilogue
  if (half == 1) {
#pragma unroll
    for (int i = 0; i < 4; ++i)
#pragma unroll
      for (int j = 0; j < 4; ++j) red[(i * 4 + j) * 256 + t] = acc[i][j];
  }
  __syncthreads();
  if (half == 0) {
#pragma unroll
    for (int i = 0; i < 4; ++i)
#pragma unroll
      for (int j = 0; j < 4; ++j) acc[i][j] += red[(i * 4 + j) * 256 + t];
#pragma unroll
    for (int i = 0; i < 4; ++i) {
      int m = m0 + ty * 4 + i;
      if (m >= M) continue;
      int nb = n0 + tx * 4;
      if (nb + 3 < N) {
        float4 v;
        v.x = acc[i][0] + (bias ? bias[nb + 0] : 0.f);
        v.y = acc[i][1] + (bias ? bias[nb + 1] : 0.f);
        v.z = acc[i][2] + (bias ? bias[nb + 2] : 0.f);
        v.w = acc[i][3] + (bias ? bias[nb + 3] : 0.f);
        if (relu) {
          v.x = v.x > 0.f ? v.x : 0.f; v.y = v.y > 0.f ? v.y : 0.f;
          v.z = v.z > 0.f ? v.z : 0.f; v.w = v.w > 0.f ? v.w : 0.f;
        }
        *(float4*)&C[(size_t)m * N + nb] = v;
      } else {
#pragma unroll
        for (int j = 0; j < 4; ++j) {
          int n = nb + j;
          if (n >= N) continue;
          float v = acc[i][j] + (bias ? bias[n] : 0.f);
          if (relu) v = v > 0.f ? v : 0.f;
          C[(size_t)m * N + n] = v;
        }
      }
    }
  }
}

// ---------------- K3: inverse row norms of henc -> rinv [NS] ---------------
__global__ __launch_bounds__(256) void k_rnorm(const float* __restrict__ henc,
                                               float* __restrict__ rinv) {
  int s = blockIdx.x * 4 + (threadIdx.x >> 6);
  int lane = threadIdx.x & 63;
  if (s >= NS) return;
  const float* src = henc + (size_t)s * HDIM;
  float ss = 0.f;
#pragma unroll
  for (int q = 0; q < 5; ++q) {
    int d = lane + q * 64;
    float x = (d < HDIM) ? src[d] : 0.f;
    ss += x * x;
  }
#pragma unroll
  for (int off = 32; off > 0; off >>= 1) ss += __shfl_down(ss, off, 64);
  if (lane == 0) rinv[s] = 1.f / (sqrtf(ss) + 1e-8f);
}

// ---------------- K4: Wcat[k][j] = [Wc_top | Wc_bot] column-concat ---------
__global__ void k_wcat(const float* __restrict__ Wc, float* __restrict__ Wcat) {
  int i = blockIdx.x * 256 + threadIdx.x;
  if (i >= HDIM * 2 * HDIM) return;
  int k = i / (2 * HDIM), j = i - k * 2 * HDIM;
  Wcat[i] = (j < HDIM) ? Wc[(size_t)k * HDIM + j]
                       : Wc[(size_t)(HDIM + k) * HDIM + (j - HDIM)];
}

// --- K5: cost GEMM, split-K halves + reg-prefetch dbuf + fused exp ---------
// 512 threads, same structure as k_gemm; A/B tiles gathered from henc with
// on-the-fly rinv normalization. One aligned float4 load per tile per thread
// (henc rows are 300 floats -> every row is 16B-aligned).
__global__ __launch_bounds__(512) void k_cost(
    const float* __restrict__ henc, const float* __restrict__ rinv,
    const int* __restrict__ ridx, const int* __restrict__ cidx,
    const int* __restrict__ rlen, const int* __restrict__ clen,
    float* __restrict__ Kmat) {
  int b = blockIdx.z;
  int r0 = blockIdx.x * 64, c0 = blockIdx.y * 64;
  int rl = rlen[b], cl = clen[b];
  float* Kg = Kmat + (size_t)b * NMAX * MMAX;
  int tid = threadIdx.x;
  if (r0 >= rl || c0 >= cl) {
    for (int l = tid; l < 64 * 16; l += 512) {
      int i = l >> 4, j = (l & 15) << 2;
      *(float4*)&Kg[(size_t)(r0 + i) * MMAX + c0 + j] =
          make_float4(0.f, 0.f, 0.f, 0.f);
    }
    return;
  }
  __shared__ int rix[64], cix[64];
  __shared__ float rnv[64], cnv[64];
  __shared__ __align__(16) float smem[2][2][2][16][68];  // [buf][half][A|B]
  float* red = &smem[0][0][0][0][0];
  int half = tid >> 8, t = tid & 255, tx = t & 15, ty = t >> 4;
  if (tid < 64) {
    int r = ridx[b * NMAX + r0 + tid];
    rix[tid] = r; rnv[tid] = rinv[r];
  } else if (tid < 128) {
    int r = cidx[b * MMAX + c0 + tid - 64];
    cix[tid - 64] = r; cnv[tid - 64] = rinv[r];
  }
  __syncthreads();
  int kbase = half * 160;
  int rowT = t >> 2, kq = t & 3;  // rowT 0..63, kq: which float4 of the chunk
  const float* aPtr = henc + (size_t)rix[rowT] * HDIM + kbase + kq * 4;
  const float* bPtr = henc + (size_t)cix[rowT] * HDIM + kbase + kq * 4;
  float aS = rnv[rowT], cS = cnv[rowT];
  float aR[4], bR[4];
  auto loadC = [&](int c) {
    int k = kbase + c * 16 + kq * 4;
    if (k + 3 < HDIM) {
      float4 a4 = *(const float4*)(aPtr + c * 16);
      float4 b4 = *(const float4*)(bPtr + c * 16);
      aR[0] = a4.x * aS; aR[1] = a4.y * aS; aR[2] = a4.z * aS; aR[3] = a4.w * aS;
      bR[0] = b4.x * cS; bR[1] = b4.y * cS; bR[2] = b4.z * cS; bR[3] = b4.w * cS;
    } else {
#pragma unroll
      for (int i = 0; i < 4; ++i) {
        bool ok = (k + i) < HDIM;
        aR[i] = ok ? aPtr[c * 16 + i] * aS : 0.f;
        bR[i] = ok ? bPtr[c * 16 + i] * cS : 0.f;
      }
    }
  };
  auto storeC = [&](int buf) {
#pragma unroll
    for (int i = 0; i < 4; ++i) smem[buf][half][0][kq * 4 + i][rowT] = aR[i];
#pragma unroll
    for (int i = 0; i < 4; ++i) smem[buf][half][1][kq * 4 + i][rowT] = bR[i];
  };
  float acc[4][4] = {};
  loadC(0);
  storeC(0);
  __syncthreads();
  int cur = 0;
  for (int c = 0; c < 10; ++c) {
    if (c < 9) loadC(c + 1);
#pragma unroll
    for (int kk = 0; kk < 16; ++kk) {
      float4 av = *(const float4*)&smem[cur][half][0][kk][ty * 4];
      float4 bv = *(const float4*)&smem[cur][half][1][kk][tx * 4];
      float a[4] = {av.x, av.y, av.z, av.w};
      float w[4] = {bv.x, bv.y, bv.z, bv.w};
#pragma unroll
      for (int i = 0; i < 4; ++i)
#pragma unroll
        for (int j = 0; j < 4; ++j) acc[i][j] += a[i] * w[j];
    }
    if (c < 9) storeC(cur ^ 1);
    __syncthreads();
    cur ^= 1;
  }
  // cross-half reduction, then exp epilogue in half 0
  if (half == 1) {
#pragma unroll
    for (int i = 0; i < 4; ++i)
#pragma unroll
      for (int j = 0; j < 4; ++j) red[(i * 4 + j) * 256 + t] = acc[i][j];
  }
  __syncthreads();
  if (half == 0) {
#pragma unroll
    for (int i = 0; i < 4; ++i)
#pragma unroll
      for (int j = 0; j < 4; ++j) acc[i][j] += red[(i * 4 + j) * 256 + t];
#pragma unroll
    for (int i = 0; i < 4; ++i) {
      int n = r0 + ty * 4 + i;
      float4 kv;
      float* kvp = &kv.x;
#pragma unroll
      for (int j = 0; j < 4; ++j) {
        int m = c0 + tx * 4 + j;
        kvp[j] = (n < rl && m < cl) ? expf((acc[i][j] - 1.f) / EPSR) : 0.f;
      }
      *(float4*)&Kg[(size_t)n * MMAX + c0 + tx * 4] = kv;
    }
  }
}

// --------- K6: Sinkhorn, K held in VGPRs (kr row / kt col slices) ----------
__global__ __launch_bounds__(512) void k_sinkhorn(
    float* __restrict__ Kmat, const int* __restrict__ rlen,
    const int* __restrict__ clen) {
  __shared__ __align__(16) float vq[4][36];
  __shared__ __align__(16) float uq[4][36];
  int b = blockIdx.x;
  int tid = threadIdx.x;
  int n = tid >> 2, q = tid & 3;
  int rl = rlen[b], cl = clen[b];
  float* Kg = Kmat + (size_t)b * NMAX * MMAX;
  float kr[32], kt[32];
  const float4* Kg4 = (const float4*)(Kg + (size_t)n * MMAX + 32 * q);
#pragma unroll
  for (int t = 0; t < 8; ++t) *(float4*)&kr[4 * t] = Kg4[t];
#pragma unroll
  for (int j = 0; j < 32; ++j) kt[j] = Kg[(size_t)(32 * q + j) * MMAX + n];
  if (tid < 128) vq[tid >> 5][tid & 31] = (tid < cl) ? 1.f : 0.f;
  float av = (n < rl) ? 1.f / (float)rl : 0.f;
  float bv = (n < cl) ? 1.f / (float)cl : 0.f;
  float un = 0.f;
  __syncthreads();
  for (int it = 0; it < SITERS; ++it) {
    float s = 0.f;
#pragma unroll
    for (int t = 0; t < 8; ++t) {
      float4 vv = *(const float4*)&vq[q][4 * t];
      s += kr[4 * t + 0] * vv.x + kr[4 * t + 1] * vv.y +
           kr[4 * t + 2] * vv.z + kr[4 * t + 3] * vv.w;
    }
    s += __shfl_xor(s, 1, 64);
    s += __shfl_xor(s, 2, 64);
    un = (n < rl) ? av / s : 0.f;
    if (q == 0) uq[n >> 5][n & 31] = un;
    __syncthreads();
    float s2 = 0.f;
#pragma unroll
    for (int t = 0; t < 8; ++t) {
      float4 uu = *(const float4*)&uq[q][4 * t];
      s2 += kt[4 * t + 0] * uu.x + kt[4 * t + 1] * uu.y +
            kt[4 * t + 2] * uu.z + kt[4 * t + 3] * uu.w;
    }
    s2 += __shfl_xor(s2, 1, 64);
    s2 += __shfl_xor(s2, 2, 64);
    float vm = (n < cl) ? bv / s2 : 0.f;
    if (q == 0) vq[n >> 5][n & 31] = vm;
    __syncthreads();
  }
  float4* Pg4 = (float4*)(Kg + (size_t)n * MMAX + 32 * q);
#pragma unroll
  for (int t = 0; t < 8; ++t) {
    float4 vv = *(const float4*)&vq[q][4 * t];
    float4 p;
    p.x = un * kr[4 * t + 0] * vv.x;
    p.y = un * kr[4 * t + 1] * vv.y;
    p.z = un * kr[4 * t + 2] * vv.z;
    p.w = un * kr[4 * t + 3] * vv.w;
    Pg4[t] = p;
  }
}

// ---- K7: attend + compare + masked sum, prefetch dbuf ---------------------
// HcB: [NS,600] = [Hc | Hcb]. main side adds HcB[.,0:300], other gathers
// HcB[.,300:600]. SIDE 0: P[i][k]; SIDE 1: P[k][j] transposed.
template <int SIDE>
__global__ __launch_bounds__(256) void k_att_cmp(
    const float* __restrict__ P, const float* __restrict__ HcB,
    const int* __restrict__ idx_main, const int* __restrict__ idx_other,
    const int* __restrict__ len_main, const int* __restrict__ len_other,
    const float* __restrict__ bc, float* __restrict__ outacc) {
  int b = blockIdx.y;
  int c0 = blockIdx.x * 64;
  int lm = len_main[b], lo = len_other[b];
  __shared__ __align__(16) float smem[2][2][16][68];  // [buf][P|G]
  __shared__ int iox[NMAX];
  __shared__ int imx[NMAX];
  int tid = threadIdx.x, tx = tid & 15, ty = tid >> 4;
  int jj = tid & 63, kq = tid >> 6;
  if (tid < 128) iox[tid] = idx_other[b * NMAX + tid];
  else imx[tid - 128] = idx_main[b * NMAX + tid - 128];
  __syncthreads();
  const float* Pb = P + (size_t)b * NMAX * MMAX;
  bool cok = (c0 + jj) < HDIM;
  int nkc = (lo + 15) >> 4;
  int nmt = (lm + 63) >> 6;
  float pR[4], gR[4];
  auto loadPG = [&](int mt, int kc) {
    int m0 = mt * 64, k0 = kc * 16;
    if (SIDE == 0) {
#pragma unroll
      for (int p = 0; p < 4; ++p)
        pR[p] = Pb[(size_t)(m0 + ty + p * 16) * MMAX + k0 + tx];
    } else {
#pragma unroll
      for (int p = 0; p < 4; ++p)
        pR[p] = Pb[(size_t)(k0 + kq + p * 4) * MMAX + m0 + jj];
    }
#pragma unroll
    for (int p = 0; p < 4; ++p) {
      int row = iox[k0 + kq + p * 4];
      gR[p] = cok ? HcB[(size_t)row * 600 + 300 + c0 + jj] : 0.f;
    }
  };
  auto storePG = [&](int buf) {
    if (SIDE == 0) {
#pragma unroll
      for (int p = 0; p < 4; ++p) smem[buf][0][tx][ty + p * 16] = pR[p];
    } else {
#pragma unroll
      for (int p = 0; p < 4; ++p) smem[buf][0][kq + p * 4][jj] = pR[p];
    }
#pragma unroll
    for (int p = 0; p < 4; ++p) smem[buf][1][kq + p * 4][jj] = gR[p];
  };
  float colsum[4] = {0.f, 0.f, 0.f, 0.f};
  loadPG(0, 0);
  storePG(0);
  __syncthreads();
  int cur = 0;
  for (int mt = 0; mt < nmt; ++mt) {
    float acc[4][4] = {};
    for (int kc = 0; kc < nkc; ++kc) {
      bool last = (mt == nmt - 1) && (kc == nkc - 1);
      if (!last) {
        int nm = (kc + 1 < nkc) ? mt : mt + 1;
        int nk = (kc + 1 < nkc) ? kc + 1 : 0;
        loadPG(nm, nk);
      }
#pragma unroll
      for (int kk = 0; kk < 16; ++kk) {
        float4 av = *(const float4*)&smem[cur][0][kk][ty * 4];
        float4 gv = *(const float4*)&smem[cur][1][kk][tx * 4];
        float a[4] = {av.x, av.y, av.z, av.w};
        float g[4] = {gv.x, gv.y, gv.z, gv.w};
#pragma unroll
        for (int i = 0; i < 4; ++i)
#pragma unroll
          for (int j = 0; j < 4; ++j) acc[i][j] += a[i] * g[j];
      }
      if (!last) storePG(cur ^ 1);
      __syncthreads();
      cur ^= 1;
    }
    // epilogue for this m-tile (registers + global only — pipeline-safe)
#pragma unroll
    for (int i = 0; i < 4; ++i) {
      int mi = mt * 64 + ty * 4 + i;
      if (mi >= lm) continue;
      int hrow = imx[mi];
#pragma unroll
      for (int j = 0; j < 4; ++j) {
        int col = c0 + tx * 4 + j;
        if (col >= HDIM) continue;
        float y = acc[i][j] + HcB[(size_t)hrow * 600 + col] + bc[col];
        colsum[j] += y > 0.f ? y : 0.f;
      }
    }
  }
  __syncthreads();
  float(*red)[68] = (float(*)[68]) & smem[0][0][0][0];
#pragma unroll
  for (int j = 0; j < 4; ++j) red[ty][tx * 4 + j] = colsum[j];
  __syncthreads();
  if (tid < 64) {
    float s = 0.f;
#pragma unroll
    for (int r = 0; r < 16; ++r) s += red[r][tid];
    int col = c0 + tid;
    if (col < HDIM) outacc[(size_t)b * HDIM + col] = s;
  }
}

// ---------------- K8: classifier head -> out [B,2] -------------------------
__global__ __launch_bounds__(320) void k_cls(
    const float* __restrict__ cr, const float* __restrict__ cc,
    const float* __restrict__ Wcls, const float* __restrict__ bcls,
    const float* __restrict__ Wout, const float* __restrict__ bout,
    float* __restrict__ out) {
  __shared__ __align__(16) float cz[2 * HDIM];
  __shared__ float zz[HDIM];
  int b = blockIdx.x, tid = threadIdx.x;
  if (tid < HDIM) {
    cz[tid] = cr[(size_t)b * HDIM + tid];
    cz[HDIM + tid] = cc[(size_t)b * HDIM + tid];
  }
  __syncthreads();
  if (tid < HDIM) {
    float acc = bcls[tid];
    for (int k4 = 0; k4 < 2 * HDIM; k4 += 4) {
      float4 c = *(const float4*)&cz[k4];
      acc += c.x * Wcls[(size_t)(k4 + 0) * HDIM + tid] +
             c.y * Wcls[(size_t)(k4 + 1) * HDIM + tid] +
             c.z * Wcls[(size_t)(k4 + 2) * HDIM + tid] +
             c.w * Wcls[(size_t)(k4 + 3) * HDIM + tid];
    }
    zz[tid] = acc > 0.f ? acc : 0.f;
  }
  __syncthreads();
  int o = tid >> 6, lane = tid & 63;
  if (o < 2) {
    float p = 0.f;
    for (int j = lane; j < HDIM; j += 64) p += zz[j] * Wout[(size_t)j * 2 + o];
#pragma unroll
    for (int off = 32; off > 0; off >>= 1) p += __shfl_down(p, off, 64);
    if (lane == 0) out[b * 2 + o] = p + bout[o];
  }
}

extern "C" void kernel_launch(void* const* d_in, const int* in_sizes, int n_in,
                              void* d_out, int out_size, void* d_ws, size_t ws_size,
                              hipStream_t stream) {
  (void)in_sizes; (void)n_in; (void)out_size; (void)ws_size;
  const int* data = (const int*)d_in[0];
  const int* row_idx = (const int*)d_in[1];
  const int* col_idx = (const int*)d_in[2];
  const int* row_len = (const int*)d_in[3];
  const int* col_len = (const int*)d_in[4];
  const float* emb = (const float*)d_in[5];
  const float* W1 = (const float*)d_in[6];
  const float* b1 = (const float*)d_in[7];
  const float* W2 = (const float*)d_in[8];
  const float* b2 = (const float*)d_in[9];
  const float* Wc = (const float*)d_in[10];
  const float* bc = (const float*)d_in[11];
  const float* Wcls = (const float*)d_in[12];
  const float* bcls = (const float*)d_in[13];
  const float* Wout = (const float*)d_in[14];
  const float* bout = (const float*)d_in[15];
  float* out = (float*)d_out;

  float* ws = (float*)d_ws;
  size_t off = 0;
  float* enc = ws + off; off += (size_t)NS * DDIM;
  float* h1 = ws + off; off += (size_t)NS * HDIM;
  float* henc = ws + off; off += (size_t)NS * HDIM;
  float* rinv = ws + off; off += NS;
  float* Wcat = ws + off; off += (size_t)HDIM * 2 * HDIM;
  float* HcB = ws + off; off += (size_t)NS * 2 * HDIM;
  float* Km = ws + off; off += (size_t)BB * NMAX * MMAX;
  float* cr = ws + off; off += (size_t)BB * HDIM;
  float* cc = ws + off; off += (size_t)BB * HDIM;

  dim3 gNS((NS + 63) / 64, (HDIM + 63) / 64);
  dim3 gNS6((NS + 63) / 64, (2 * HDIM + 63) / 64);

  k_embed<<<NS, 256, 0, stream>>>(data, emb, enc);
  k_wcat<<<(HDIM * 2 * HDIM + 255) / 256, 256, 0, stream>>>(Wc, Wcat);
  k_gemm<<<gNS, 512, 0, stream>>>(enc, W1, b1, h1, NS, HDIM, DDIM, 1);
  k_gemm<<<gNS, 512, 0, stream>>>(h1, W2, b2, henc, NS, HDIM, HDIM, 1);
  k_rnorm<<<(NS + 3) / 4, 256, 0, stream>>>(henc, rinv);
  k_gemm<<<gNS6, 512, 0, stream>>>(henc, Wcat, nullptr, HcB, NS, 2 * HDIM,
                                   HDIM, 0);
  k_cost<<<dim3(2, 2, BB), 512, 0, stream>>>(henc, rinv, row_idx, col_idx,
                                             row_len, col_len, Km);
  k_sinkhorn<<<BB, 512, 0, stream>>>(Km, row_len, col_len);
  k_att_cmp<0><<<dim3(5, BB), 256, 0, stream>>>(
      Km, HcB, row_idx, col_idx, row_len, col_len, bc, cr);
  k_att_cmp<1><<<dim3(5, BB), 256, 0, stream>>>(
      Km, HcB, col_idx, row_idx, col_len, row_len, bc, cc);
  k_cls<<<BB, 320, 0, stream>>>(cr, cc, Wcls, bcls, Wout, bout, out);
}

// Round 8
// 449.809 us; speedup vs baseline: 1.7070x; 1.1409x over previous
//
#include <hip/hip_runtime.h>
#include <math.h>

#define NS 10000
#define LSEQ 32
#define DDIM 300
#define HDIM 300
#define BB 256
#define NMAX 128
#define MMAX 128
#define EPSR 0.1f
#define SITERS 50
#define KPAD 320

typedef __attribute__((ext_vector_type(8))) short bf16x8;
typedef __attribute__((ext_vector_type(4))) float f32x4;

__device__ __forceinline__ ushort f2bf(float x) {
  union { float f; unsigned u; } c; c.f = x;
  unsigned r = (c.u + 0x7fffu + ((c.u >> 16) & 1u)) >> 16;
  return (ushort)r;
}
__device__ __forceinline__ float bf2f(ushort h) {
  union { unsigned u; float f; } c; c.u = ((unsigned)h) << 16;
  return c.f;
}

// ------- K1: embedding + masked mean pool -> enc hi/lo [NS][KPAD] bf16 -----
__global__ __launch_bounds__(256) void k_embed(const int* __restrict__ data,
                                               const float* __restrict__ emb,
                                               ushort* __restrict__ enchi,
                                               ushort* __restrict__ enclo) {
  __shared__ int ids[LSEQ];
  __shared__ __align__(16) float4 part[3][76];
  int s = blockIdx.x;
  int tid = threadIdx.x;
  if (tid < LSEQ) ids[tid] = data[s * LSEQ + tid];
  __syncthreads();
  int cnt = 0;
#pragma unroll
  for (int t = 0; t < LSEQ; ++t) cnt += (ids[t] != 0) ? 1 : 0;
  int g = tid / 75, d = tid - g * 75;
  const float4* emb4 = (const float4*)emb;
  if (g < 3) {
    float4 acc = make_float4(0.f, 0.f, 0.f, 0.f);
    for (int t = g; t < LSEQ; t += 3) {
      int id = ids[t];
      if (id != 0) {
        float4 e = emb4[(size_t)id * 75 + d];
        acc.x += e.x; acc.y += e.y; acc.z += e.z; acc.w += e.w;
      }
    }
    part[g][d] = acc;
  }
  __syncthreads();
  if (g == 0) {
    float4 a = part[0][d], b = part[1][d], c = part[2][d];
    float inv = 1.f / (float)(cnt > 0 ? cnt : 1);
    float v[4] = {(a.x + b.x + c.x) * inv, (a.y + b.y + c.y) * inv,
                  (a.z + b.z + c.z) * inv, (a.w + b.w + c.w) * inv};
    ushort4 h, l;
    h.x = f2bf(v[0]); l.x = f2bf(v[0] - bf2f(h.x));
    h.y = f2bf(v[1]); l.y = f2bf(v[1] - bf2f(h.y));
    h.z = f2bf(v[2]); l.z = f2bf(v[2] - bf2f(h.z));
    h.w = f2bf(v[3]); l.w = f2bf(v[3] - bf2f(h.w));
    *(ushort4*)&enchi[(size_t)s * KPAD + d * 4] = h;
    *(ushort4*)&enclo[(size_t)s * KPAD + d * 4] = l;
  } else if (g == 1 && d < 5) {
    ushort4 z; z.x = z.y = z.z = z.w = 0;
    *(ushort4*)&enchi[(size_t)s * KPAD + 300 + d * 4] = z;
    *(ushort4*)&enclo[(size_t)s * KPAD + 300 + d * 4] = z;
  }
}

// ------- K2: weight convert [K][N] f32 -> transposed hi/lo [Npad][KPAD] ----
__global__ __launch_bounds__(256) void k_cvtw(const float* __restrict__ W,
                                              ushort* __restrict__ hiT,
                                              ushort* __restrict__ loT,
                                              int K, int N, int Npad) {
  int idx = blockIdx.x * 256 + threadIdx.x;
  if (idx >= Npad * KPAD) return;
  int n = idx / KPAD, k = idx - n * KPAD;
  float v = (n < N && k < K) ? W[(size_t)k * N + n] : 0.f;
  ushort h = f2bf(v);
  hiT[idx] = h;
  loT[idx] = f2bf(v - bf2f(h));
}

// ------- K3: Wcat transpose+split straight from Wc [600][300] --------------
// Wcat[k][j] = j<300 ? Wc[k][j] : Wc[300+k][j-300]; out [640][KPAD] hi/lo
__global__ __launch_bounds__(256) void k_cvtwc(const float* __restrict__ Wc,
                                               ushort* __restrict__ hiT,
                                               ushort* __restrict__ loT) {
  int idx = blockIdx.x * 256 + threadIdx.x;
  if (idx >= 640 * KPAD) return;
  int n = idx / KPAD, k = idx - n * KPAD;
  float v = 0.f;
  if (k < 300 && n < 600)
    v = (n < 300) ? Wc[(size_t)k * 300 + n]
                  : Wc[(size_t)(300 + k) * 300 + (n - 300)];
  ushort h = f2bf(v);
  hiT[idx] = h;
  loT[idx] = f2bf(v - bf2f(h));
}

// ------- K4: MFMA GEMM, bf16 hi/lo split (3-term), 64x64 tile --------------
// A: hi/lo [M][KPAD] bf16. B: hi/lo transposed [Npad][KPAD] bf16.
// 256 thr = 4 waves; wave w owns rows [w*16,w*16+16), 4 n-subtiles of 16.
// Outputs: optional f32 C [M][N]; optional hi/lo [M][KPAD] (cols>=N zeroed).
__global__ __launch_bounds__(256) void k_gemm_mfma(
    const ushort* __restrict__ Ahi, const ushort* __restrict__ Alo,
    const ushort* __restrict__ BhiT, const ushort* __restrict__ BloT,
    const float* __restrict__ bias, int M, int N, int relu,
    float* __restrict__ Cf, ushort* __restrict__ Chi,
    ushort* __restrict__ Clo) {
  __shared__ ushort lds[4][64][40];  // Ahi,Alo,Bhi,Blo; row pad 40 (16B align)
  int tid = threadIdx.x;
  int m0 = blockIdx.x * 64, n0 = blockIdx.y * 64;
  int row = tid >> 2, ch = tid & 3;
  bool mok = (m0 + row) < M;
  const ushort* pAh = Ahi + (size_t)(m0 + row) * KPAD + ch * 8;
  const ushort* pAl = Alo + (size_t)(m0 + row) * KPAD + ch * 8;
  const ushort* pBh = BhiT + (size_t)(n0 + row) * KPAD + ch * 8;
  const ushort* pBl = BloT + (size_t)(n0 + row) * KPAD + ch * 8;
  uint4 rAh, rAl, rBh, rBl;
  uint4 z4; z4.x = z4.y = z4.z = z4.w = 0;
  auto ld = [&](int c) {
    int o = c * 32;
    rAh = mok ? *(const uint4*)(pAh + o) : z4;
    rAl = mok ? *(const uint4*)(pAl + o) : z4;
    rBh = *(const uint4*)(pBh + o);
    rBl = *(const uint4*)(pBl + o);
  };
  auto st = [&]() {
    *(uint4*)&lds[0][row][ch * 8] = rAh;
    *(uint4*)&lds[1][row][ch * 8] = rAl;
    *(uint4*)&lds[2][row][ch * 8] = rBh;
    *(uint4*)&lds[3][row][ch * 8] = rBl;
  };
  int w = tid >> 6, lane = tid & 63;
  int q = lane >> 4, l16 = lane & 15;
  int arow = w * 16 + l16;
  f32x4 acc[4] = {{0.f, 0.f, 0.f, 0.f}, {0.f, 0.f, 0.f, 0.f},
                  {0.f, 0.f, 0.f, 0.f}, {0.f, 0.f, 0.f, 0.f}};
  ld(0); st(); __syncthreads();
  for (int c = 0; c < 10; ++c) {
    if (c < 9) ld(c + 1);
    bf16x8 ah = *(const bf16x8*)&lds[0][arow][q * 8];
    bf16x8 al = *(const bf16x8*)&lds[1][arow][q * 8];
#pragma unroll
    for (int t = 0; t < 4; ++t) {
      int brow = t * 16 + l16;
      bf16x8 bh = *(const bf16x8*)&lds[2][brow][q * 8];
      bf16x8 bl = *(const bf16x8*)&lds[3][brow][q * 8];
      acc[t] = __builtin_amdgcn_mfma_f32_16x16x32_bf16(ah, bh, acc[t], 0, 0, 0);
      acc[t] = __builtin_amdgcn_mfma_f32_16x16x32_bf16(ah, bl, acc[t], 0, 0, 0);
      acc[t] = __builtin_amdgcn_mfma_f32_16x16x32_bf16(al, bh, acc[t], 0, 0, 0);
    }
    __syncthreads();
    if (c < 9) st();
    __syncthreads();
  }
  // epilogue: D[m=quad*4+r][n=l16] per subtile (verified m89 C/D mapping)
#pragma unroll
  for (int t = 0; t < 4; ++t) {
    int n = n0 + t * 16 + l16;
    bool nin = n < N;
    float bz = (bias && nin) ? bias[n] : 0.f;
#pragma unroll
    for (int r = 0; r < 4; ++r) {
      int m = m0 + w * 16 + q * 4 + r;
      if (m >= M) continue;
      float v = acc[t][r] + bz;
      if (relu) v = v > 0.f ? v : 0.f;
      if (Cf && nin) Cf[(size_t)m * N + n] = v;
      if (Chi) {
        ushort h = 0, l = 0;
        if (nin) { h = f2bf(v); l = f2bf(v - bf2f(h)); }
        Chi[(size_t)m * KPAD + n] = h;
        Clo[(size_t)m * KPAD + n] = l;
      }
    }
  }
}

// ---------------- K5: inverse row norms of henc -> rinv [NS] ---------------
__global__ __launch_bounds__(256) void k_rnorm(const float* __restrict__ henc,
                                               float* __restrict__ rinv) {
  int s = blockIdx.x * 4 + (threadIdx.x >> 6);
  int lane = threadIdx.x & 63;
  if (s >= NS) return;
  const float* src = henc + (size_t)s * HDIM;
  float ss = 0.f;
#pragma unroll
  for (int q = 0; q < 5; ++q) {
    int d = lane + q * 64;
    float x = (d < HDIM) ? src[d] : 0.f;
    ss += x * x;
  }
#pragma unroll
  for (int off = 32; off > 0; off >>= 1) ss += __shfl_down(ss, off, 64);
  if (lane == 0) rinv[s] = 1.f / (sqrtf(ss) + 1e-8f);
}

// --- K6: cost GEMM, split-K halves + reg-prefetch dbuf + fused exp ---------
__global__ __launch_bounds__(512) void k_cost(
    const float* __restrict__ henc, const float* __restrict__ rinv,
    const int* __restrict__ ridx, const int* __restrict__ cidx,
    const int* __restrict__ rlen, const int* __restrict__ clen,
    float* __restrict__ Kmat) {
  int b = blockIdx.z;
  int r0 = blockIdx.x * 64, c0 = blockIdx.y * 64;
  int rl = rlen[b], cl = clen[b];
  float* Kg = Kmat + (size_t)b * NMAX * MMAX;
  int tid = threadIdx.x;
  if (r0 >= rl || c0 >= cl) {
    for (int l = tid; l < 64 * 16; l += 512) {
      int i = l >> 4, j = (l & 15) << 2;
      *(float4*)&Kg[(size_t)(r0 + i) * MMAX + c0 + j] =
          make_float4(0.f, 0.f, 0.f, 0.f);
    }
    return;
  }
  __shared__ int rix[64], cix[64];
  __shared__ float rnv[64], cnv[64];
  __shared__ __align__(16) float smem[2][2][2][16][68];  // [buf][half][A|B]
  float* red = &smem[0][0][0][0][0];
  int half = tid >> 8, t = tid & 255, tx = t & 15, ty = t >> 4;
  if (tid < 64) {
    int r = ridx[b * NMAX + r0 + tid];
    rix[tid] = r; rnv[tid] = rinv[r];
  } else if (tid < 128) {
    int r = cidx[b * MMAX + c0 + tid - 64];
    cix[tid - 64] = r; cnv[tid - 64] = rinv[r];
  }
  __syncthreads();
  int kbase = half * 160;
  int rowT = t >> 2, kq = t & 3;
  const float* aPtr = henc + (size_t)rix[rowT] * HDIM + kbase + kq * 4;
  const float* bPtr = henc + (size_t)cix[rowT] * HDIM + kbase + kq * 4;
  float aS = rnv[rowT], cS = cnv[rowT];
  float aR[4], bR[4];
  auto loadC = [&](int c) {
    int k = kbase + c * 16 + kq * 4;
    if (k + 3 < HDIM) {
      float4 a4 = *(const float4*)(aPtr + c * 16);
      float4 b4 = *(const float4*)(bPtr + c * 16);
      aR[0] = a4.x * aS; aR[1] = a4.y * aS; aR[2] = a4.z * aS; aR[3] = a4.w * aS;
      bR[0] = b4.x * cS; bR[1] = b4.y * cS; bR[2] = b4.z * cS; bR[3] = b4.w * cS;
    } else {
#pragma unroll
      for (int i = 0; i < 4; ++i) {
        bool ok = (k + i) < HDIM;
        aR[i] = ok ? aPtr[c * 16 + i] * aS : 0.f;
        bR[i] = ok ? bPtr[c * 16 + i] * cS : 0.f;
      }
    }
  };
  auto storeC = [&](int buf) {
#pragma unroll
    for (int i = 0; i < 4; ++i) smem[buf][half][0][kq * 4 + i][rowT] = aR[i];
#pragma unroll
    for (int i = 0; i < 4; ++i) smem[buf][half][1][kq * 4 + i][rowT] = bR[i];
  };
  float acc[4][4] = {};
  loadC(0);
  storeC(0);
  __syncthreads();
  int cur = 0;
  for (int c = 0; c < 10; ++c) {
    if (c < 9) loadC(c + 1);
#pragma unroll
    for (int kk = 0; kk < 16; ++kk) {
      float4 av = *(const float4*)&smem[cur][half][0][kk][ty * 4];
      float4 bv = *(const float4*)&smem[cur][half][1][kk][tx * 4];
      float a[4] = {av.x, av.y, av.z, av.w};
      float w[4] = {bv.x, bv.y, bv.z, bv.w};
#pragma unroll
      for (int i = 0; i < 4; ++i)
#pragma unroll
        for (int j = 0; j < 4; ++j) acc[i][j] += a[i] * w[j];
    }
    if (c < 9) storeC(cur ^ 1);
    __syncthreads();
    cur ^= 1;
  }
  if (half == 1) {
#pragma unroll
    for (int i = 0; i < 4; ++i)
#pragma unroll
      for (int j = 0; j < 4; ++j) red[(i * 4 + j) * 256 + t] = acc[i][j];
  }
  __syncthreads();
  if (half == 0) {
#pragma unroll
    for (int i = 0; i < 4; ++i)
#pragma unroll
      for (int j = 0; j < 4; ++j) acc[i][j] += red[(i * 4 + j) * 256 + t];
#pragma unroll
    for (int i = 0; i < 4; ++i) {
      int n = r0 + ty * 4 + i;
      float4 kv;
      float* kvp = &kv.x;
#pragma unroll
      for (int j = 0; j < 4; ++j) {
        int m = c0 + tx * 4 + j;
        kvp[j] = (n < rl && m < cl) ? expf((acc[i][j] - 1.f) / EPSR) : 0.f;
      }
      *(float4*)&Kg[(size_t)n * MMAX + c0 + tx * 4] = kv;
    }
  }
}

// --------- K7: Sinkhorn, K held in VGPRs (kr row / kt col slices) ----------
__global__ __launch_bounds__(512) void k_sinkhorn(
    float* __restrict__ Kmat, const int* __restrict__ rlen,
    const int* __restrict__ clen) {
  __shared__ __align__(16) float vq[4][36];
  __shared__ __align__(16) float uq[4][36];
  int b = blockIdx.x;
  int tid = threadIdx.x;
  int n = tid >> 2, q = tid & 3;
  int rl = rlen[b], cl = clen[b];
  float* Kg = Kmat + (size_t)b * NMAX * MMAX;
  float kr[32], kt[32];
  const float4* Kg4 = (const float4*)(Kg + (size_t)n * MMAX + 32 * q);
#pragma unroll
  for (int t = 0; t < 8; ++t) *(float4*)&kr[4 * t] = Kg4[t];
#pragma unroll
  for (int j = 0; j < 32; ++j) kt[j] = Kg[(size_t)(32 * q + j) * MMAX + n];
  if (tid < 128) vq[tid >> 5][tid & 31] = (tid < cl) ? 1.f : 0.f;
  float av = (n < rl) ? 1.f / (float)rl : 0.f;
  float bv = (n < cl) ? 1.f / (float)cl : 0.f;
  float un = 0.f;
  __syncthreads();
  for (int it = 0; it < SITERS; ++it) {
    float s = 0.f;
#pragma unroll
    for (int t = 0; t < 8; ++t) {
      float4 vv = *(const float4*)&vq[q][4 * t];
      s += kr[4 * t + 0] * vv.x + kr[4 * t + 1] * vv.y +
           kr[4 * t + 2] * vv.z + kr[4 * t + 3] * vv.w;
    }
    s += __shfl_xor(s, 1, 64);
    s += __shfl_xor(s, 2, 64);
    un = (n < rl) ? av / s : 0.f;
    if (q == 0) uq[n >> 5][n & 31] = un;
    __syncthreads();
    float s2 = 0.f;
#pragma unroll
    for (int t = 0; t < 8; ++t) {
      float4 uu = *(const float4*)&uq[q][4 * t];
      s2 += kt[4 * t + 0] * uu.x + kt[4 * t + 1] * uu.y +
            kt[4 * t + 2] * uu.z + kt[4 * t + 3] * uu.w;
    }
    s2 += __shfl_xor(s2, 1, 64);
    s2 += __shfl_xor(s2, 2, 64);
    float vm = (n < cl) ? bv / s2 : 0.f;
    if (q == 0) vq[n >> 5][n & 31] = vm;
    __syncthreads();
  }
  float4* Pg4 = (float4*)(Kg + (size_t)n * MMAX + 32 * q);
#pragma unroll
  for (int t = 0; t < 8; ++t) {
    float4 vv = *(const float4*)&vq[q][4 * t];
    float4 p;
    p.x = un * kr[4 * t + 0] * vv.x;
    p.y = un * kr[4 * t + 1] * vv.y;
    p.z = un * kr[4 * t + 2] * vv.z;
    p.w = un * kr[4 * t + 3] * vv.w;
    Pg4[t] = p;
  }
}

// ---- K8: attend + compare + masked sum, prefetch dbuf ---------------------
template <int SIDE>
__global__ __launch_bounds__(256) void k_att_cmp(
    const float* __restrict__ P, const float* __restrict__ HcB,
    const int* __restrict__ idx_main, const int* __restrict__ idx_other,
    const int* __restrict__ len_main, const int* __restrict__ len_other,
    const float* __restrict__ bc, float* __restrict__ outacc) {
  int b = blockIdx.y;
  int c0 = blockIdx.x * 64;
  int lm = len_main[b], lo = len_other[b];
  __shared__ __align__(16) float smem[2][2][16][68];  // [buf][P|G]
  __shared__ int iox[NMAX];
  __shared__ int imx[NMAX];
  int tid = threadIdx.x, tx = tid & 15, ty = tid >> 4;
  int jj = tid & 63, kq = tid >> 6;
  if (tid < 128) iox[tid] = idx_other[b * NMAX + tid];
  else imx[tid - 128] = idx_main[b * NMAX + tid - 128];
  __syncthreads();
  const float* Pb = P + (size_t)b * NMAX * MMAX;
  bool cok = (c0 + jj) < HDIM;
  int nkc = (lo + 15) >> 4;
  int nmt = (lm + 63) >> 6;
  float pR[4], gR[4];
  auto loadPG = [&](int mt, int kc) {
    int m0 = mt * 64, k0 = kc * 16;
    if (SIDE == 0) {
#pragma unroll
      for (int p = 0; p < 4; ++p)
        pR[p] = Pb[(size_t)(m0 + ty + p * 16) * MMAX + k0 + tx];
    } else {
#pragma unroll
      for (int p = 0; p < 4; ++p)
        pR[p] = Pb[(size_t)(k0 + kq + p * 4) * MMAX + m0 + jj];
    }
#pragma unroll
    for (int p = 0; p < 4; ++p) {
      int row = iox[k0 + kq + p * 4];
      gR[p] = cok ? HcB[(size_t)row * 600 + 300 + c0 + jj] : 0.f;
    }
  };
  auto storePG = [&](int buf) {
    if (SIDE == 0) {
#pragma unroll
      for (int p = 0; p < 4; ++p) smem[buf][0][tx][ty + p * 16] = pR[p];
    } else {
#pragma unroll
      for (int p = 0; p < 4; ++p) smem[buf][0][kq + p * 4][jj] = pR[p];
    }
#pragma unroll
    for (int p = 0; p < 4; ++p) smem[buf][1][kq + p * 4][jj] = gR[p];
  };
  float colsum[4] = {0.f, 0.f, 0.f, 0.f};
  loadPG(0, 0);
  storePG(0);
  __syncthreads();
  int cur = 0;
  for (int mt = 0; mt < nmt; ++mt) {
    float acc[4][4] = {};
    for (int kc = 0; kc < nkc; ++kc) {
      bool last = (mt == nmt - 1) && (kc == nkc - 1);
      if (!last) {
        int nm = (kc + 1 < nkc) ? mt : mt + 1;
        int nk = (kc + 1 < nkc) ? kc + 1 : 0;
        loadPG(nm, nk);
      }
#pragma unroll
      for (int kk = 0; kk < 16; ++kk) {
        float4 av = *(const float4*)&smem[cur][0][kk][ty * 4];
        float4 gv = *(const float4*)&smem[cur][1][kk][tx * 4];
        float a[4] = {av.x, av.y, av.z, av.w};
        float g[4] = {gv.x, gv.y, gv.z, gv.w};
#pragma unroll
        for (int i = 0; i < 4; ++i)
#pragma unroll
          for (int j = 0; j < 4; ++j) acc[i][j] += a[i] * g[j];
      }
      if (!last) storePG(cur ^ 1);
      __syncthreads();
      cur ^= 1;
    }
#pragma unroll
    for (int i = 0; i < 4; ++i) {
      int mi = mt * 64 + ty * 4 + i;
      if (mi >= lm) continue;
      int hrow = imx[mi];
#pragma unroll
      for (int j = 0; j < 4; ++j) {
        int col = c0 + tx * 4 + j;
        if (col >= HDIM) continue;
        float y = acc[i][j] + HcB[(size_t)hrow * 600 + col] + bc[col];
        colsum[j] += y > 0.f ? y : 0.f;
      }
    }
  }
  __syncthreads();
  float(*red)[68] = (float(*)[68]) & smem[0][0][0][0];
#pragma unroll
  for (int j = 0; j < 4; ++j) red[ty][tx * 4 + j] = colsum[j];
  __syncthreads();
  if (tid < 64) {
    float s = 0.f;
#pragma unroll
    for (int r = 0; r < 16; ++r) s += red[r][tid];
    int col = c0 + tid;
    if (col < HDIM) outacc[(size_t)b * HDIM + col] = s;
  }
}

// ---------------- K9: classifier head -> out [B,2] -------------------------
__global__ __launch_bounds__(320) void k_cls(
    const float* __restrict__ cr, const float* __restrict__ cc,
    const float* __restrict__ Wcls, const float* __restrict__ bcls,
    const float* __restrict__ Wout, const float* __restrict__ bout,
    float* __restrict__ out) {
  __shared__ __align__(16) float cz[2 * HDIM];
  __shared__ float zz[HDIM];
  int b = blockIdx.x, tid = threadIdx.x;
  if (tid < HDIM) {
    cz[tid] = cr[(size_t)b * HDIM + tid];
    cz[HDIM + tid] = cc[(size_t)b * HDIM + tid];
  }
  __syncthreads();
  if (tid < HDIM) {
    float acc = bcls[tid];
    for (int k4 = 0; k4 < 2 * HDIM; k4 += 4) {
      float4 c = *(const float4*)&cz[k4];
      acc += c.x * Wcls[(size_t)(k4 + 0) * HDIM + tid] +
             c.y * Wcls[(size_t)(k4 + 1) * HDIM + tid] +
             c.z * Wcls[(size_t)(k4 + 2) * HDIM + tid] +
             c.w * Wcls[(size_t)(k4 + 3) * HDIM + tid];
    }
    zz[tid] = acc > 0.f ? acc : 0.f;
  }
  __syncthreads();
  int o = tid >> 6, lane = tid & 63;
  if (o < 2) {
    float p = 0.f;
    for (int j = lane; j < HDIM; j += 64) p += zz[j] * Wout[(size_t)j * 2 + o];
#pragma unroll
    for (int off = 32; off > 0; off >>= 1) p += __shfl_down(p, off, 64);
    if (lane == 0) out[b * 2 + o] = p + bout[o];
  }
}

extern "C" void kernel_launch(void* const* d_in, const int* in_sizes, int n_in,
                              void* d_out, int out_size, void* d_ws, size_t ws_size,
                              hipStream_t stream) {
  (void)in_sizes; (void)n_in; (void)out_size; (void)ws_size;
  const int* data = (const int*)d_in[0];
  const int* row_idx = (const int*)d_in[1];
  const int* col_idx = (const int*)d_in[2];
  const int* row_len = (const int*)d_in[3];
  const int* col_len = (const int*)d_in[4];
  const float* emb = (const float*)d_in[5];
  const float* W1 = (const float*)d_in[6];
  const float* b1 = (const float*)d_in[7];
  const float* W2 = (const float*)d_in[8];
  const float* b2 = (const float*)d_in[9];
  const float* Wc = (const float*)d_in[10];
  const float* bc = (const float*)d_in[11];
  const float* Wcls = (const float*)d_in[12];
  const float* bcls = (const float*)d_in[13];
  const float* Wout = (const float*)d_in[14];
  const float* bout = (const float*)d_in[15];
  float* out = (float*)d_out;

  char* wp = (char*)d_ws;
  auto carve = [&](size_t bytes) {
    char* p = wp; wp += (bytes + 255) & ~(size_t)255; return p;
  };
  ushort* enchi = (ushort*)carve((size_t)NS * KPAD * 2);
  ushort* enclo = (ushort*)carve((size_t)NS * KPAD * 2);
  ushort* h1hi = (ushort*)carve((size_t)NS * KPAD * 2);
  ushort* h1lo = (ushort*)carve((size_t)NS * KPAD * 2);
  ushort* hehi = (ushort*)carve((size_t)NS * KPAD * 2);
  ushort* helo = (ushort*)carve((size_t)NS * KPAD * 2);
  float* henc = (float*)carve((size_t)NS * HDIM * 4);
  ushort* W1hi = (ushort*)carve((size_t)KPAD * KPAD * 2);
  ushort* W1lo = (ushort*)carve((size_t)KPAD * KPAD * 2);
  ushort* W2hi = (ushort*)carve((size_t)KPAD * KPAD * 2);
  ushort* W2lo = (ushort*)carve((size_t)KPAD * KPAD * 2);
  ushort* Wchi = (ushort*)carve((size_t)640 * KPAD * 2);
  ushort* Wclo = (ushort*)carve((size_t)640 * KPAD * 2);
  float* HcB = (float*)carve((size_t)NS * 600 * 4);
  float* Km = (float*)carve((size_t)BB * NMAX * MMAX * 4);
  float* rinv = (float*)carve((size_t)NS * 4);
  float* cr = (float*)carve((size_t)BB * HDIM * 4);
  float* cc = (float*)carve((size_t)BB * HDIM * 4);

  int gM = (NS + 63) / 64;  // 157

  k_embed<<<NS, 256, 0, stream>>>(data, emb, enchi, enclo);
  k_cvtw<<<(KPAD * KPAD + 255) / 256, 256, 0, stream>>>(W1, W1hi, W1lo, DDIM,
                                                        HDIM, KPAD);
  k_cvtw<<<(KPAD * KPAD + 255) / 256, 256, 0, stream>>>(W2, W2hi, W2lo, HDIM,
                                                        HDIM, KPAD);
  k_cvtwc<<<(640 * KPAD + 255) / 256, 256, 0, stream>>>(Wc, Wchi, Wclo);
  k_gemm_mfma<<<dim3(gM, 5), 256, 0, stream>>>(
      enchi, enclo, W1hi, W1lo, b1, NS, HDIM, 1, nullptr, h1hi, h1lo);
  k_gemm_mfma<<<dim3(gM, 5), 256, 0, stream>>>(
      h1hi, h1lo, W2hi, W2lo, b2, NS, HDIM, 1, henc, hehi, helo);
  k_rnorm<<<(NS + 3) / 4, 256, 0, stream>>>(henc, rinv);
  k_gemm_mfma<<<dim3(gM, 10), 256, 0, stream>>>(
      hehi, helo, Wchi, Wclo, nullptr, NS, 2 * HDIM, 0, HcB, nullptr, nullptr);
  k_cost<<<dim3(2, 2, BB), 512, 0, stream>>>(henc, rinv, row_idx, col_idx,
                                             row_len, col_len, Km);
  k_sinkhorn<<<BB, 512, 0, stream>>>(Km, row_len, col_len);
  k_att_cmp<0><<<dim3(5, BB), 256, 0, stream>>>(
      Km, HcB, row_idx, col_idx, row_len, col_len, bc, cr);
  k_att_cmp<1><<<dim3(5, BB), 256, 0, stream>>>(
      Km, HcB, col_idx, row_idx, col_len, row_len, bc, cc);
  k_cls<<<BB, 320, 0, stream>>>(cr, cc, Wcls, bcls, Wout, bout, out);
}

// Round 9
// 428.329 us; speedup vs baseline: 1.7927x; 1.0501x over previous
//
#include <hip/hip_runtime.h>
#include <math.h>

#define NS 10000
#define LSEQ 32
#define DDIM 300
#define HDIM 300
#define BB 256
#define NMAX 128
#define MMAX 128
#define EPSR 0.1f
#define SITERS 50
#define KPAD 320

typedef __attribute__((ext_vector_type(8))) short bf16x8;
typedef __attribute__((ext_vector_type(4))) float f32x4;

__device__ __forceinline__ ushort f2bf(float x) {
  union { float f; unsigned u; } c; c.f = x;
  unsigned r = (c.u + 0x7fffu + ((c.u >> 16) & 1u)) >> 16;
  return (ushort)r;
}
__device__ __forceinline__ float bf2f(ushort h) {
  union { unsigned u; float f; } c; c.u = ((unsigned)h) << 16;
  return c.f;
}

// ------- K1: embedding + masked mean pool -> enc hi/lo [NS][KPAD] bf16 -----
__global__ __launch_bounds__(256) void k_embed(const int* __restrict__ data,
                                               const float* __restrict__ emb,
                                               ushort* __restrict__ enchi,
                                               ushort* __restrict__ enclo) {
  __shared__ int ids[LSEQ];
  __shared__ __align__(16) float4 part[3][76];
  int s = blockIdx.x;
  int tid = threadIdx.x;
  if (tid < LSEQ) ids[tid] = data[s * LSEQ + tid];
  __syncthreads();
  int cnt = 0;
#pragma unroll
  for (int t = 0; t < LSEQ; ++t) cnt += (ids[t] != 0) ? 1 : 0;
  int g = tid / 75, d = tid - g * 75;
  const float4* emb4 = (const float4*)emb;
  if (g < 3) {
    float4 acc = make_float4(0.f, 0.f, 0.f, 0.f);
    for (int t = g; t < LSEQ; t += 3) {
      int id = ids[t];
      if (id != 0) {
        float4 e = emb4[(size_t)id * 75 + d];
        acc.x += e.x; acc.y += e.y; acc.z += e.z; acc.w += e.w;
      }
    }
    part[g][d] = acc;
  }
  __syncthreads();
  if (g == 0) {
    float4 a = part[0][d], b = part[1][d], c = part[2][d];
    float inv = 1.f / (float)(cnt > 0 ? cnt : 1);
    float v[4] = {(a.x + b.x + c.x) * inv, (a.y + b.y + c.y) * inv,
                  (a.z + b.z + c.z) * inv, (a.w + b.w + c.w) * inv};
    ushort4 h, l;
    h.x = f2bf(v[0]); l.x = f2bf(v[0] - bf2f(h.x));
    h.y = f2bf(v[1]); l.y = f2bf(v[1] - bf2f(h.y));
    h.z = f2bf(v[2]); l.z = f2bf(v[2] - bf2f(h.z));
    h.w = f2bf(v[3]); l.w = f2bf(v[3] - bf2f(h.w));
    *(ushort4*)&enchi[(size_t)s * KPAD + d * 4] = h;
    *(ushort4*)&enclo[(size_t)s * KPAD + d * 4] = l;
  } else if (g == 1 && d < 5) {
    ushort4 z; z.x = z.y = z.z = z.w = 0;
    *(ushort4*)&enchi[(size_t)s * KPAD + 300 + d * 4] = z;
    *(ushort4*)&enclo[(size_t)s * KPAD + 300 + d * 4] = z;
  }
}

// ------- K2: weight convert [K][N] f32 -> transposed hi/lo [Npad][KPAD] ----
__global__ __launch_bounds__(256) void k_cvtw(const float* __restrict__ W,
                                              ushort* __restrict__ hiT,
                                              ushort* __restrict__ loT,
                                              int K, int N, int Npad) {
  int idx = blockIdx.x * 256 + threadIdx.x;
  if (idx >= Npad * KPAD) return;
  int n = idx / KPAD, k = idx - n * KPAD;
  float v = (n < N && k < K) ? W[(size_t)k * N + n] : 0.f;
  ushort h = f2bf(v);
  hiT[idx] = h;
  loT[idx] = f2bf(v - bf2f(h));
}

// ------- K3: Wcat transpose+split straight from Wc [600][300] --------------
__global__ __launch_bounds__(256) void k_cvtwc(const float* __restrict__ Wc,
                                               ushort* __restrict__ hiT,
                                               ushort* __restrict__ loT) {
  int idx = blockIdx.x * 256 + threadIdx.x;
  if (idx >= 640 * KPAD) return;
  int n = idx / KPAD, k = idx - n * KPAD;
  float v = 0.f;
  if (k < 300 && n < 600)
    v = (n < 300) ? Wc[(size_t)k * 300 + n]
                  : Wc[(size_t)(300 + k) * 300 + (n - 300)];
  ushort h = f2bf(v);
  hiT[idx] = h;
  loT[idx] = f2bf(v - bf2f(h));
}

// ------- K4: MFMA GEMM, bf16 hi/lo split (3-term), 64x64 tile --------------
__global__ __launch_bounds__(256) void k_gemm_mfma(
    const ushort* __restrict__ Ahi, const ushort* __restrict__ Alo,
    const ushort* __restrict__ BhiT, const ushort* __restrict__ BloT,
    const float* __restrict__ bias, int M, int N, int relu,
    float* __restrict__ Cf, ushort* __restrict__ Chi,
    ushort* __restrict__ Clo) {
  __shared__ __align__(16) ushort lds[4][64][40];
  int tid = threadIdx.x;
  int m0 = blockIdx.x * 64, n0 = blockIdx.y * 64;
  int row = tid >> 2, ch = tid & 3;
  bool mok = (m0 + row) < M;
  const ushort* pAh = Ahi + (size_t)(m0 + row) * KPAD + ch * 8;
  const ushort* pAl = Alo + (size_t)(m0 + row) * KPAD + ch * 8;
  const ushort* pBh = BhiT + (size_t)(n0 + row) * KPAD + ch * 8;
  const ushort* pBl = BloT + (size_t)(n0 + row) * KPAD + ch * 8;
  uint4 rAh, rAl, rBh, rBl;
  uint4 z4; z4.x = z4.y = z4.z = z4.w = 0;
  auto ld = [&](int c) {
    int o = c * 32;
    rAh = mok ? *(const uint4*)(pAh + o) : z4;
    rAl = mok ? *(const uint4*)(pAl + o) : z4;
    rBh = *(const uint4*)(pBh + o);
    rBl = *(const uint4*)(pBl + o);
  };
  auto st = [&]() {
    *(uint4*)&lds[0][row][ch * 8] = rAh;
    *(uint4*)&lds[1][row][ch * 8] = rAl;
    *(uint4*)&lds[2][row][ch * 8] = rBh;
    *(uint4*)&lds[3][row][ch * 8] = rBl;
  };
  int w = tid >> 6, lane = tid & 63;
  int q = lane >> 4, l16 = lane & 15;
  int arow = w * 16 + l16;
  f32x4 acc[4] = {{0.f, 0.f, 0.f, 0.f}, {0.f, 0.f, 0.f, 0.f},
                  {0.f, 0.f, 0.f, 0.f}, {0.f, 0.f, 0.f, 0.f}};
  ld(0); st(); __syncthreads();
  for (int c = 0; c < 10; ++c) {
    if (c < 9) ld(c + 1);
    bf16x8 ah = *(const bf16x8*)&lds[0][arow][q * 8];
    bf16x8 al = *(const bf16x8*)&lds[1][arow][q * 8];
#pragma unroll
    for (int t = 0; t < 4; ++t) {
      int brow = t * 16 + l16;
      bf16x8 bh = *(const bf16x8*)&lds[2][brow][q * 8];
      bf16x8 bl = *(const bf16x8*)&lds[3][brow][q * 8];
      acc[t] = __builtin_amdgcn_mfma_f32_16x16x32_bf16(ah, bh, acc[t], 0, 0, 0);
      acc[t] = __builtin_amdgcn_mfma_f32_16x16x32_bf16(ah, bl, acc[t], 0, 0, 0);
      acc[t] = __builtin_amdgcn_mfma_f32_16x16x32_bf16(al, bh, acc[t], 0, 0, 0);
    }
    __syncthreads();
    if (c < 9) st();
    __syncthreads();
  }
#pragma unroll
  for (int t = 0; t < 4; ++t) {
    int n = n0 + t * 16 + l16;
    bool nin = n < N;
    float bz = (bias && nin) ? bias[n] : 0.f;
#pragma unroll
    for (int r = 0; r < 4; ++r) {
      int m = m0 + w * 16 + q * 4 + r;
      if (m >= M) continue;
      float v = acc[t][r] + bz;
      if (relu) v = v > 0.f ? v : 0.f;
      if (Cf && nin) Cf[(size_t)m * N + n] = v;
      if (Chi) {
        ushort h = 0, l = 0;
        if (nin) { h = f2bf(v); l = f2bf(v - bf2f(h)); }
        Chi[(size_t)m * KPAD + n] = h;
        Clo[(size_t)m * KPAD + n] = l;
      }
    }
  }
}

// --- K5: normalize henc (hi/lo) -> hn hi/lo [NS][KPAD] (unit rows) ---------
__global__ __launch_bounds__(256) void k_norm_split(
    const ushort* __restrict__ hehi, const ushort* __restrict__ helo,
    ushort* __restrict__ hnhi, ushort* __restrict__ hnlo) {
  int s = blockIdx.x * 4 + (threadIdx.x >> 6);
  int lane = threadIdx.x & 63;
  if (s >= NS) return;
  const ushort* ph = hehi + (size_t)s * KPAD;
  const ushort* pl = helo + (size_t)s * KPAD;
  float x[5];
  float ss = 0.f;
#pragma unroll
  for (int q = 0; q < 5; ++q) {
    int d = lane + q * 64;
    x[q] = bf2f(ph[d]) + bf2f(pl[d]);  // pad cols are 0
    ss += x[q] * x[q];
  }
#pragma unroll
  for (int off = 32; off > 0; off >>= 1) ss += __shfl_down(ss, off, 64);
  ss = __shfl(ss, 0, 64);
  float inv = 1.f / (sqrtf(ss) + 1e-8f);
  ushort* qh = hnhi + (size_t)s * KPAD;
  ushort* ql = hnlo + (size_t)s * KPAD;
#pragma unroll
  for (int q = 0; q < 5; ++q) {
    int d = lane + q * 64;
    float v = x[q] * inv;
    ushort h = f2bf(v);
    qh[d] = h;
    ql[d] = f2bf(v - bf2f(h));
  }
}

// --- K6: cost as gathered MFMA GEMM (hn·hn^T) + fused exp ------------------
// A = hn[ridx rows], B^T = hn[cidx rows] — both [row][k] like k_gemm_mfma.
__global__ __launch_bounds__(256) void k_cost_mfma(
    const ushort* __restrict__ hnhi, const ushort* __restrict__ hnlo,
    const int* __restrict__ ridx, const int* __restrict__ cidx,
    const int* __restrict__ rlen, const int* __restrict__ clen,
    float* __restrict__ Kmat) {
  int b = blockIdx.z;
  int r0 = blockIdx.x * 64, c0 = blockIdx.y * 64;
  int rl = rlen[b], cl = clen[b];
  float* Kg = Kmat + (size_t)b * NMAX * MMAX;
  int tid = threadIdx.x;
  if (r0 >= rl || c0 >= cl) {
    for (int l = tid; l < 64 * 16; l += 256) {
      int i = l >> 4, j = (l & 15) << 2;
      *(float4*)&Kg[(size_t)(r0 + i) * MMAX + c0 + j] =
          make_float4(0.f, 0.f, 0.f, 0.f);
    }
    return;
  }
  __shared__ int rix[64], cix[64];
  __shared__ __align__(16) ushort lds[4][64][40];  // Rhi,Rlo,Chi,Clo
  if (tid < 64) rix[tid] = ridx[b * NMAX + r0 + tid];
  else if (tid < 128) cix[tid - 64] = cidx[b * MMAX + c0 + tid - 64];
  __syncthreads();
  int row = tid >> 2, ch = tid & 3;
  const ushort* pRh = hnhi + (size_t)rix[row] * KPAD + ch * 8;
  const ushort* pRl = hnlo + (size_t)rix[row] * KPAD + ch * 8;
  const ushort* pCh = hnhi + (size_t)cix[row] * KPAD + ch * 8;
  const ushort* pCl = hnlo + (size_t)cix[row] * KPAD + ch * 8;
  uint4 rRh, rRl, rCh, rCl;
  auto ld = [&](int c) {
    int o = c * 32;
    rRh = *(const uint4*)(pRh + o);
    rRl = *(const uint4*)(pRl + o);
    rCh = *(const uint4*)(pCh + o);
    rCl = *(const uint4*)(pCl + o);
  };
  auto st = [&]() {
    *(uint4*)&lds[0][row][ch * 8] = rRh;
    *(uint4*)&lds[1][row][ch * 8] = rRl;
    *(uint4*)&lds[2][row][ch * 8] = rCh;
    *(uint4*)&lds[3][row][ch * 8] = rCl;
  };
  int w = tid >> 6, lane = tid & 63;
  int q = lane >> 4, l16 = lane & 15;
  int arow = w * 16 + l16;
  f32x4 acc[4] = {{0.f, 0.f, 0.f, 0.f}, {0.f, 0.f, 0.f, 0.f},
                  {0.f, 0.f, 0.f, 0.f}, {0.f, 0.f, 0.f, 0.f}};
  ld(0); st(); __syncthreads();
  for (int c = 0; c < 10; ++c) {
    if (c < 9) ld(c + 1);
    bf16x8 ah = *(const bf16x8*)&lds[0][arow][q * 8];
    bf16x8 al = *(const bf16x8*)&lds[1][arow][q * 8];
#pragma unroll
    for (int t = 0; t < 4; ++t) {
      int brow = t * 16 + l16;
      bf16x8 bh = *(const bf16x8*)&lds[2][brow][q * 8];
      bf16x8 bl = *(const bf16x8*)&lds[3][brow][q * 8];
      acc[t] = __builtin_amdgcn_mfma_f32_16x16x32_bf16(ah, bh, acc[t], 0, 0, 0);
      acc[t] = __builtin_amdgcn_mfma_f32_16x16x32_bf16(ah, bl, acc[t], 0, 0, 0);
      acc[t] = __builtin_amdgcn_mfma_f32_16x16x32_bf16(al, bh, acc[t], 0, 0, 0);
    }
    __syncthreads();
    if (c < 9) st();
    __syncthreads();
  }
  // D[m = w*16+q*4+r (r-side)][n = t*16+l16 (c-side)]; exp epilogue
#pragma unroll
  for (int t = 0; t < 4; ++t) {
    int n = c0 + t * 16 + l16;
#pragma unroll
    for (int r = 0; r < 4; ++r) {
      int m = r0 + w * 16 + q * 4 + r;
      float kv = (m < rl && n < cl) ? expf((acc[t][r] - 1.f) / EPSR) : 0.f;
      Kg[(size_t)m * MMAX + n] = kv;
    }
  }
}

// --------- K7: Sinkhorn, K held in VGPRs (kr row / kt col slices) ----------
__global__ __launch_bounds__(512) void k_sinkhorn(
    float* __restrict__ Kmat, const int* __restrict__ rlen,
    const int* __restrict__ clen) {
  __shared__ __align__(16) float vq[4][36];
  __shared__ __align__(16) float uq[4][36];
  int b = blockIdx.x;
  int tid = threadIdx.x;
  int n = tid >> 2, q = tid & 3;
  int rl = rlen[b], cl = clen[b];
  float* Kg = Kmat + (size_t)b * NMAX * MMAX;
  float kr[32], kt[32];
  const float4* Kg4 = (const float4*)(Kg + (size_t)n * MMAX + 32 * q);
#pragma unroll
  for (int t = 0; t < 8; ++t) *(float4*)&kr[4 * t] = Kg4[t];
#pragma unroll
  for (int j = 0; j < 32; ++j) kt[j] = Kg[(size_t)(32 * q + j) * MMAX + n];
  if (tid < 128) vq[tid >> 5][tid & 31] = (tid < cl) ? 1.f : 0.f;
  float av = (n < rl) ? 1.f / (float)rl : 0.f;
  float bv = (n < cl) ? 1.f / (float)cl : 0.f;
  float un = 0.f;
  __syncthreads();
  for (int it = 0; it < SITERS; ++it) {
    float s = 0.f;
#pragma unroll
    for (int t = 0; t < 8; ++t) {
      float4 vv = *(const float4*)&vq[q][4 * t];
      s += kr[4 * t + 0] * vv.x + kr[4 * t + 1] * vv.y +
           kr[4 * t + 2] * vv.z + kr[4 * t + 3] * vv.w;
    }
    s += __shfl_xor(s, 1, 64);
    s += __shfl_xor(s, 2, 64);
    un = (n < rl) ? av / s : 0.f;
    if (q == 0) uq[n >> 5][n & 31] = un;
    __syncthreads();
    float s2 = 0.f;
#pragma unroll
    for (int t = 0; t < 8; ++t) {
      float4 uu = *(const float4*)&uq[q][4 * t];
      s2 += kt[4 * t + 0] * uu.x + kt[4 * t + 1] * uu.y +
            kt[4 * t + 2] * uu.z + kt[4 * t + 3] * uu.w;
    }
    s2 += __shfl_xor(s2, 1, 64);
    s2 += __shfl_xor(s2, 2, 64);
    float vm = (n < cl) ? bv / s2 : 0.f;
    if (q == 0) vq[n >> 5][n & 31] = vm;
    __syncthreads();
  }
  float4* Pg4 = (float4*)(Kg + (size_t)n * MMAX + 32 * q);
#pragma unroll
  for (int t = 0; t < 8; ++t) {
    float4 vv = *(const float4*)&vq[q][4 * t];
    float4 p;
    p.x = un * kr[4 * t + 0] * vv.x;
    p.y = un * kr[4 * t + 1] * vv.y;
    p.z = un * kr[4 * t + 2] * vv.z;
    p.w = un * kr[4 * t + 3] * vv.w;
    Pg4[t] = p;
  }
}

// ---- K8: attend + compare + masked sum, prefetch dbuf ---------------------
template <int SIDE>
__global__ __launch_bounds__(256) void k_att_cmp(
    const float* __restrict__ P, const float* __restrict__ HcB,
    const int* __restrict__ idx_main, const int* __restrict__ idx_other,
    const int* __restrict__ len_main, const int* __restrict__ len_other,
    const float* __restrict__ bc, float* __restrict__ outacc) {
  int b = blockIdx.y;
  int c0 = blockIdx.x * 64;
  int lm = len_main[b], lo = len_other[b];
  __shared__ __align__(16) float smem[2][2][16][68];  // [buf][P|G]
  __shared__ int iox[NMAX];
  __shared__ int imx[NMAX];
  int tid = threadIdx.x, tx = tid & 15, ty = tid >> 4;
  int jj = tid & 63, kq = tid >> 6;
  if (tid < 128) iox[tid] = idx_other[b * NMAX + tid];
  else imx[tid - 128] = idx_main[b * NMAX + tid - 128];
  __syncthreads();
  const float* Pb = P + (size_t)b * NMAX * MMAX;
  bool cok = (c0 + jj) < HDIM;
  int nkc = (lo + 15) >> 4;
  int nmt = (lm + 63) >> 6;
  float pR[4], gR[4];
  auto loadPG = [&](int mt, int kc) {
    int m0 = mt * 64, k0 = kc * 16;
    if (SIDE == 0) {
#pragma unroll
      for (int p = 0; p < 4; ++p)
        pR[p] = Pb[(size_t)(m0 + ty + p * 16) * MMAX + k0 + tx];
    } else {
#pragma unroll
      for (int p = 0; p < 4; ++p)
        pR[p] = Pb[(size_t)(k0 + kq + p * 4) * MMAX + m0 + jj];
    }
#pragma unroll
    for (int p = 0; p < 4; ++p) {
      int row = iox[k0 + kq + p * 4];
      gR[p] = cok ? HcB[(size_t)row * 600 + 300 + c0 + jj] : 0.f;
    }
  };
  auto storePG = [&](int buf) {
    if (SIDE == 0) {
#pragma unroll
      for (int p = 0; p < 4; ++p) smem[buf][0][tx][ty + p * 16] = pR[p];
    } else {
#pragma unroll
      for (int p = 0; p < 4; ++p) smem[buf][0][kq + p * 4][jj] = pR[p];
    }
#pragma unroll
    for (int p = 0; p < 4; ++p) smem[buf][1][kq + p * 4][jj] = gR[p];
  };
  float colsum[4] = {0.f, 0.f, 0.f, 0.f};
  loadPG(0, 0);
  storePG(0);
  __syncthreads();
  int cur = 0;
  for (int mt = 0; mt < nmt; ++mt) {
    float acc[4][4] = {};
    for (int kc = 0; kc < nkc; ++kc) {
      bool last = (mt == nmt - 1) && (kc == nkc - 1);
      if (!last) {
        int nm = (kc + 1 < nkc) ? mt : mt + 1;
        int nk = (kc + 1 < nkc) ? kc + 1 : 0;
        loadPG(nm, nk);
      }
#pragma unroll
      for (int kk = 0; kk < 16; ++kk) {
        float4 av = *(const float4*)&smem[cur][0][kk][ty * 4];
        float4 gv = *(const float4*)&smem[cur][1][kk][tx * 4];
        float a[4] = {av.x, av.y, av.z, av.w};
        float g[4] = {gv.x, gv.y, gv.z, gv.w};
#pragma unroll
        for (int i = 0; i < 4; ++i)
#pragma unroll
          for (int j = 0; j < 4; ++j) acc[i][j] += a[i] * g[j];
      }
      if (!last) storePG(cur ^ 1);
      __syncthreads();
      cur ^= 1;
    }
#pragma unroll
    for (int i = 0; i < 4; ++i) {
      int mi = mt * 64 + ty * 4 + i;
      if (mi >= lm) continue;
      int hrow = imx[mi];
#pragma unroll
      for (int j = 0; j < 4; ++j) {
        int col = c0 + tx * 4 + j;
        if (col >= HDIM) continue;
        float y = acc[i][j] + HcB[(size_t)hrow * 600 + col] + bc[col];
        colsum[j] += y > 0.f ? y : 0.f;
      }
    }
  }
  __syncthreads();
  float(*red)[68] = (float(*)[68]) & smem[0][0][0][0];
#pragma unroll
  for (int j = 0; j < 4; ++j) red[ty][tx * 4 + j] = colsum[j];
  __syncthreads();
  if (tid < 64) {
    float s = 0.f;
#pragma unroll
    for (int r = 0; r < 16; ++r) s += red[r][tid];
    int col = c0 + tid;
    if (col < HDIM) outacc[(size_t)b * HDIM + col] = s;
  }
}

// ---------------- K9: classifier head -> out [B,2] -------------------------
__global__ __launch_bounds__(320) void k_cls(
    const float* __restrict__ cr, const float* __restrict__ cc,
    const float* __restrict__ Wcls, const float* __restrict__ bcls,
    const float* __restrict__ Wout, const float* __restrict__ bout,
    float* __restrict__ out) {
  __shared__ __align__(16) float cz[2 * HDIM];
  __shared__ float zz[HDIM];
  int b = blockIdx.x, tid = threadIdx.x;
  if (tid < HDIM) {
    cz[tid] = cr[(size_t)b * HDIM + tid];
    cz[HDIM + tid] = cc[(size_t)b * HDIM + tid];
  }
  __syncthreads();
  if (tid < HDIM) {
    float acc = bcls[tid];
    for (int k4 = 0; k4 < 2 * HDIM; k4 += 4) {
      float4 c = *(const float4*)&cz[k4];
      acc += c.x * Wcls[(size_t)(k4 + 0) * HDIM + tid] +
             c.y * Wcls[(size_t)(k4 + 1) * HDIM + tid] +
             c.z * Wcls[(size_t)(k4 + 2) * HDIM + tid] +
             c.w * Wcls[(size_t)(k4 + 3) * HDIM + tid];
    }
    zz[tid] = acc > 0.f ? acc : 0.f;
  }
  __syncthreads();
  int o = tid >> 6, lane = tid & 63;
  if (o < 2) {
    float p = 0.f;
    for (int j = lane; j < HDIM; j += 64) p += zz[j] * Wout[(size_t)j * 2 + o];
#pragma unroll
    for (int off = 32; off > 0; off >>= 1) p += __shfl_down(p, off, 64);
    if (lane == 0) out[b * 2 + o] = p + bout[o];
  }
}

extern "C" void kernel_launch(void* const* d_in, const int* in_sizes, int n_in,
                              void* d_out, int out_size, void* d_ws, size_t ws_size,
                              hipStream_t stream) {
  (void)in_sizes; (void)n_in; (void)out_size; (void)ws_size;
  const int* data = (const int*)d_in[0];
  const int* row_idx = (const int*)d_in[1];
  const int* col_idx = (const int*)d_in[2];
  const int* row_len = (const int*)d_in[3];
  const int* col_len = (const int*)d_in[4];
  const float* emb = (const float*)d_in[5];
  const float* W1 = (const float*)d_in[6];
  const float* b1 = (const float*)d_in[7];
  const float* W2 = (const float*)d_in[8];
  const float* b2 = (const float*)d_in[9];
  const float* Wc = (const float*)d_in[10];
  const float* bc = (const float*)d_in[11];
  const float* Wcls = (const float*)d_in[12];
  const float* bcls = (const float*)d_in[13];
  const float* Wout = (const float*)d_in[14];
  const float* bout = (const float*)d_in[15];
  float* out = (float*)d_out;

  char* wp = (char*)d_ws;
  auto carve = [&](size_t bytes) {
    char* p = wp; wp += (bytes + 255) & ~(size_t)255; return p;
  };
  ushort* enchi = (ushort*)carve((size_t)NS * KPAD * 2);
  ushort* enclo = (ushort*)carve((size_t)NS * KPAD * 2);
  ushort* h1hi = (ushort*)carve((size_t)NS * KPAD * 2);
  ushort* h1lo = (ushort*)carve((size_t)NS * KPAD * 2);
  ushort* hehi = (ushort*)carve((size_t)NS * KPAD * 2);
  ushort* helo = (ushort*)carve((size_t)NS * KPAD * 2);
  ushort* hnhi = (ushort*)carve((size_t)NS * KPAD * 2);
  ushort* hnlo = (ushort*)carve((size_t)NS * KPAD * 2);
  ushort* W1hi = (ushort*)carve((size_t)KPAD * KPAD * 2);
  ushort* W1lo = (ushort*)carve((size_t)KPAD * KPAD * 2);
  ushort* W2hi = (ushort*)carve((size_t)KPAD * KPAD * 2);
  ushort* W2lo = (ushort*)carve((size_t)KPAD * KPAD * 2);
  ushort* Wchi = (ushort*)carve((size_t)640 * KPAD * 2);
  ushort* Wclo = (ushort*)carve((size_t)640 * KPAD * 2);
  float* HcB = (float*)carve((size_t)NS * 600 * 4);
  float* Km = (float*)carve((size_t)BB * NMAX * MMAX * 4);
  float* cr = (float*)carve((size_t)BB * HDIM * 4);
  float* cc = (float*)carve((size_t)BB * HDIM * 4);

  int gM = (NS + 63) / 64;  // 157

  k_embed<<<NS, 256, 0, stream>>>(data, emb, enchi, enclo);
  k_cvtw<<<(KPAD * KPAD + 255) / 256, 256, 0, stream>>>(W1, W1hi, W1lo, DDIM,
                                                        HDIM, KPAD);
  k_cvtw<<<(KPAD * KPAD + 255) / 256, 256, 0, stream>>>(W2, W2hi, W2lo, HDIM,
                                                        HDIM, KPAD);
  k_cvtwc<<<(640 * KPAD + 255) / 256, 256, 0, stream>>>(Wc, Wchi, Wclo);
  k_gemm_mfma<<<dim3(gM, 5), 256, 0, stream>>>(
      enchi, enclo, W1hi, W1lo, b1, NS, HDIM, 1, nullptr, h1hi, h1lo);
  k_gemm_mfma<<<dim3(gM, 5), 256, 0, stream>>>(
      h1hi, h1lo, W2hi, W2lo, b2, NS, HDIM, 1, nullptr, hehi, helo);
  k_norm_split<<<(NS + 3) / 4, 256, 0, stream>>>(hehi, helo, hnhi, hnlo);
  k_gemm_mfma<<<dim3(gM, 10), 256, 0, stream>>>(
      hehi, helo, Wchi, Wclo, nullptr, NS, 2 * HDIM, 0, HcB, nullptr, nullptr);
  k_cost_mfma<<<dim3(2, 2, BB), 256, 0, stream>>>(hnhi, hnlo, row_idx, col_idx,
                                                  row_len, col_len, Km);
  k_sinkhorn<<<BB, 512, 0, stream>>>(Km, row_len, col_len);
  k_att_cmp<0><<<dim3(5, BB), 256, 0, stream>>>(
      Km, HcB, row_idx, col_idx, row_len, col_len, bc, cr);
  k_att_cmp<1><<<dim3(5, BB), 256, 0, stream>>>(
      Km, HcB, col_idx, row_idx, col_len, row_len, bc, cc);
  k_cls<<<BB, 320, 0, stream>>>(cr, cc, Wcls, bcls, Wout, bout, out);
}